// Round 2
// baseline (1099.122 us; speedup 1.0000x reference)
//
#include <hip/hip_runtime.h>
#include <cstddef>
#include <cstdint>

#define ALPHA 0.9f
#define BETA  0.8f

// ---------------- sizes ----------------
// state [256,3,224,224]
// conv1: 32x3x8x8 s4 -> [256,32,55,55]
// conv2: 64x32x4x4 s2 -> [256,64,26,26]
// conv3: 64x64x3x3 s1 -> [256,64,24,24] -> feats 36864
// base = feats(36864) + history(90) = 36954
// fc1: 128 x 36954 ; fc2: 256 x 128 ; fc3: 9 x 256
#define FEAT   36864
#define HIST   90
#define K1     36954

// ---------------- conv1 ----------------
__global__ __launch_bounds__(256) void conv1_ker(const float* __restrict__ in,
    const float* __restrict__ w, const float* __restrict__ bias, float* __restrict__ out)
{
  __shared__ float wl[192 * 32];   // [k][cout]
  int t = threadIdx.x;
  for (int idx = t; idx < 6144; idx += 256) {
    int co = idx / 192, k = idx % 192;
    wl[k * 32 + co] = w[idx];
  }
  __syncthreads();
  int b = blockIdx.y;
  int pos = blockIdx.x * 256 + t;
  if (pos >= 55 * 55) return;
  int y = pos / 55, x = pos % 55;
  const float* ip = in + (size_t)b * 3 * 224 * 224;
  float acc[32];
#pragma unroll
  for (int q = 0; q < 32; ++q) acc[q] = 0.f;
  for (int c = 0; c < 3; ++c) {
#pragma unroll
    for (int kh = 0; kh < 8; ++kh) {
      const float* r = ip + (size_t)(c * 224 + (y * 4 + kh)) * 224 + x * 4;
      const float4 i0 = *(const float4*)(r);
      const float4 i1 = *(const float4*)(r + 4);
      float iv[8] = {i0.x, i0.y, i0.z, i0.w, i1.x, i1.y, i1.z, i1.w};
#pragma unroll
      for (int kw = 0; kw < 8; ++kw) {
        const float4* wp = (const float4*)(wl + ((c * 8 + kh) * 8 + kw) * 32);
#pragma unroll
        for (int q = 0; q < 8; ++q) {
          float4 wv = wp[q];
          acc[q * 4 + 0] += iv[kw] * wv.x;
          acc[q * 4 + 1] += iv[kw] * wv.y;
          acc[q * 4 + 2] += iv[kw] * wv.z;
          acc[q * 4 + 3] += iv[kw] * wv.w;
        }
      }
    }
  }
  size_t ob = (size_t)b * 32 * 3025 + pos;
#pragma unroll
  for (int q = 0; q < 32; ++q) {
    float v = acc[q] + bias[q];
    out[ob + (size_t)q * 3025] = v > 0.f ? v : 0.f;
  }
}

// ---------------- conv2 ----------------
__global__ __launch_bounds__(256) void conv2_ker(const float* __restrict__ in,
    const float* __restrict__ w, const float* __restrict__ bias, float* __restrict__ out)
{
  __shared__ float wl[512 * 16];   // [k][cout_local]
  int t = threadIdx.x;
  int g = blockIdx.x;   // cout group 0..3 (16 each)
  int b = blockIdx.y;
  for (int idx = t; idx < 8192; idx += 256) {
    int q = idx / 512, k = idx % 512;
    wl[k * 16 + q] = w[(size_t)(g * 16 + q) * 512 + k];
  }
  __syncthreads();
  const float* ip = in + (size_t)b * 32 * 3025;
  for (int pos = t; pos < 26 * 26; pos += 256) {
    int y = pos / 26, x = pos % 26;
    float acc[16];
#pragma unroll
    for (int q = 0; q < 16; ++q) acc[q] = 0.f;
    for (int c = 0; c < 32; ++c) {
#pragma unroll
      for (int kh = 0; kh < 4; ++kh) {
        const float* r = ip + (size_t)(c * 55 + (y * 2 + kh)) * 55 + x * 2;
#pragma unroll
        for (int kw = 0; kw < 4; ++kw) {
          float iv = r[kw];
          const float4* wp = (const float4*)(wl + ((c * 16 + kh * 4 + kw) << 4));
#pragma unroll
          for (int q = 0; q < 4; ++q) {
            float4 wv = wp[q];
            acc[q * 4 + 0] += iv * wv.x;
            acc[q * 4 + 1] += iv * wv.y;
            acc[q * 4 + 2] += iv * wv.z;
            acc[q * 4 + 3] += iv * wv.w;
          }
        }
      }
    }
    size_t ob = ((size_t)b * 64 + g * 16) * 676 + pos;
#pragma unroll
    for (int q = 0; q < 16; ++q) {
      float v = acc[q] + bias[g * 16 + q];
      out[ob + (size_t)q * 676] = v > 0.f ? v : 0.f;
    }
  }
}

// ---------------- conv3 (writes feats layout [b][c][y][x]) ----------------
__global__ __launch_bounds__(256) void conv3_ker(const float* __restrict__ in,
    const float* __restrict__ w, const float* __restrict__ bias, float* __restrict__ feats)
{
  __shared__ float wl[576 * 16];
  int t = threadIdx.x;
  int g = blockIdx.x;   // 0..3
  int b = blockIdx.y;
  for (int idx = t; idx < 9216; idx += 256) {
    int q = idx / 576, k = idx % 576;
    wl[k * 16 + q] = w[(size_t)(g * 16 + q) * 576 + k];
  }
  __syncthreads();
  const float* ip = in + (size_t)b * 64 * 676;
  for (int pos = t; pos < 24 * 24; pos += 256) {
    int y = pos / 24, x = pos % 24;
    float acc[16];
#pragma unroll
    for (int q = 0; q < 16; ++q) acc[q] = 0.f;
    for (int c = 0; c < 64; ++c) {
#pragma unroll
      for (int kh = 0; kh < 3; ++kh) {
        const float* r = ip + (size_t)(c * 26 + (y + kh)) * 26 + x;
#pragma unroll
        for (int kw = 0; kw < 3; ++kw) {
          float iv = r[kw];
          const float4* wp = (const float4*)(wl + ((c * 9 + kh * 3 + kw) << 4));
#pragma unroll
          for (int q = 0; q < 4; ++q) {
            float4 wv = wp[q];
            acc[q * 4 + 0] += iv * wv.x;
            acc[q * 4 + 1] += iv * wv.y;
            acc[q * 4 + 2] += iv * wv.z;
            acc[q * 4 + 3] += iv * wv.w;
          }
        }
      }
    }
    size_t ob = (size_t)b * FEAT + (size_t)(g * 16) * 576 + pos;
#pragma unroll
    for (int q = 0; q < 16; ++q) {
      float v = acc[q] + bias[g * 16 + q];
      feats[ob + (size_t)q * 576] = v > 0.f ? v : 0.f;
    }
  }
}

// ---------------- fc1 weight transpose: [128][36954] -> [36954][128] ----------------
__global__ __launch_bounds__(256) void transpose_fc1(const float* __restrict__ w,
                                                     float* __restrict__ wT)
{
  __shared__ float tl[32][130];
  int t = threadIdx.x;
  int k0 = blockIdx.x * 32;
  for (int e = t; e < 4096; e += 256) {
    int o = e >> 5, j = e & 31;
    int k = k0 + j;
    tl[j][o] = (k < K1) ? w[(size_t)o * K1 + k] : 0.f;
  }
  __syncthreads();
  for (int e = t; e < 4096; e += 256) {
    int j = e >> 7, o = e & 127;
    int k = k0 + j;
    if (k < K1) wT[(size_t)k * 128 + o] = tl[j][o];
  }
}

// ---------------- fc2 weight transpose: [256][128] -> [128][256] ----------------
__global__ __launch_bounds__(256) void transpose_fc2(const float* __restrict__ w,
                                                     float* __restrict__ wT)
{
  int idx = blockIdx.x * 256 + threadIdx.x;
  if (idx < 128 * 256) {
    int i = idx >> 8, j = idx & 255;
    wT[idx] = w[j * 128 + i];
  }
}

// ---- fc1 split-K: partials to h1part[ks][256*128], deterministic reduce after ----
__global__ __launch_bounds__(256) void fc1_ker(const float* __restrict__ feats,
    const float* __restrict__ hist, const float* __restrict__ wT, float* __restrict__ h1part)
{
  __shared__ float al[32][33];
  int t = threadIdx.x;
  int ks = blockIdx.x;            // 0..31 split-K
  int b0 = blockIdx.y * 32;       // sample tile
  int kbeg = ks * 1155;
  int kend = kbeg + 1155; if (kend > K1) kend = K1;
  int sl = t >> 3, og = t & 7;
  float acc[16];
#pragma unroll
  for (int j = 0; j < 16; ++j) acc[j] = 0.f;
  for (int k0 = kbeg; k0 < kend; k0 += 32) {
    for (int e = t; e < 1024; e += 256) {
      int s = e >> 5, kk = e & 31;
      int k = k0 + kk;
      float v = 0.f;
      if (k < kend)
        v = (k < FEAT) ? feats[(size_t)(b0 + s) * FEAT + k]
                       : hist[(size_t)(b0 + s) * HIST + (k - FEAT)];
      al[s][kk] = v;
    }
    __syncthreads();
    int klim = kend - k0; if (klim > 32) klim = 32;
    for (int kk = 0; kk < klim; ++kk) {
      float a = al[sl][kk];
      const float4* wp = (const float4*)(wT + (size_t)(k0 + kk) * 128 + og * 16);
      float4 w0 = wp[0], w1 = wp[1], w2 = wp[2], w3 = wp[3];
      acc[0]  += a * w0.x; acc[1]  += a * w0.y; acc[2]  += a * w0.z; acc[3]  += a * w0.w;
      acc[4]  += a * w1.x; acc[5]  += a * w1.y; acc[6]  += a * w1.z; acc[7]  += a * w1.w;
      acc[8]  += a * w2.x; acc[9]  += a * w2.y; acc[10] += a * w2.z; acc[11] += a * w2.w;
      acc[12] += a * w3.x; acc[13] += a * w3.y; acc[14] += a * w3.z; acc[15] += a * w3.w;
    }
    __syncthreads();
  }
  float* hp = h1part + (size_t)ks * 32768 + (size_t)(b0 + sl) * 128 + og * 16;
#pragma unroll
  for (int j = 0; j < 16; ++j) hp[j] = acc[j];
}

// ---------------- fixed-order split-K reduce: h1[i] = sum_ks part[ks][i] ----------------
__global__ __launch_bounds__(256) void fc1_reduce(const float* __restrict__ h1part,
                                                  float* __restrict__ h1)
{
  int i = blockIdx.x * 256 + threadIdx.x;
  if (i >= 32768) return;
  float s = 0.f;
#pragma unroll 1
  for (int ks = 0; ks < 32; ++ks) s += h1part[(size_t)ks * 32768 + i];
  h1[i] = s;
}

// ---------------- SNN simulation: one block per sample ----------------
__global__ __launch_bounds__(256) void snn_ker(const float* __restrict__ h1,
    const float* __restrict__ b1, const float* __restrict__ w2T,
    const float* __restrict__ b2p, const float* __restrict__ w3,
    const float* __restrict__ b3p, float* __restrict__ out)
{
  int b = blockIdx.x, t = threadIdx.x;
  __shared__ float spk1l[128];
  __shared__ float part[4][9];
  float h1v = 0.f;
  if (t < 128) h1v = h1[b * 128 + t] + b1[t];
  float b2 = b2p[t];
  float w3r[9];
#pragma unroll
  for (int j = 0; j < 9; ++j) w3r[j] = w3[j * 256 + t];
  float mem1 = 0.f, syn1 = 0.f, mem2 = 0.f, syn2 = 0.f;
  float syn3[9], mem3[9], pot[9];
#pragma unroll
  for (int j = 0; j < 9; ++j) { syn3[j] = 0.f; mem3[j] = 0.f; pot[j] = 0.f; }

#pragma unroll 1
  for (int step = 0; step < 10; ++step) {
    if (t < 128) {
      syn1 = ALPHA * syn1 + h1v;
      mem1 = BETA * mem1 + syn1;
      float s = (mem1 > 1.0f) ? 1.f : 0.f;
      spk1l[t] = s;
      mem1 -= s;
    }
    __syncthreads();
    float h2 = b2;
    for (int i = 0; i < 128; ++i) {
      if (spk1l[i] != 0.f) h2 += w2T[i * 256 + t];
    }
    syn2 = ALPHA * syn2 + h2;
    mem2 = BETA * mem2 + syn2;
    float s2 = (mem2 > 1.0f) ? 1.f : 0.f;
    mem2 -= s2;

    float v[9];
#pragma unroll
    for (int j = 0; j < 9; ++j) v[j] = s2 * w3r[j];
#pragma unroll
    for (int j = 0; j < 9; ++j) {
      v[j] += __shfl_down(v[j], 32);
      v[j] += __shfl_down(v[j], 16);
      v[j] += __shfl_down(v[j], 8);
      v[j] += __shfl_down(v[j], 4);
      v[j] += __shfl_down(v[j], 2);
      v[j] += __shfl_down(v[j], 1);
    }
    if ((t & 63) == 0) {
#pragma unroll
      for (int j = 0; j < 9; ++j) part[t >> 6][j] = v[j];
    }
    __syncthreads();
    if (t == 0) {
#pragma unroll
      for (int j = 0; j < 9; ++j) {
        float h3 = part[0][j] + part[1][j] + part[2][j] + part[3][j] + b3p[j];
        syn3[j] = ALPHA * syn3[j] + h3;
        mem3[j] = BETA * mem3[j] + syn3[j];
        pot[j] += mem3[j];
      }
    }
    // next write to part happens after the next top-of-step __syncthreads -> safe
  }
  if (t == 0) {
#pragma unroll
    for (int j = 0; j < 9; ++j) out[b * 9 + j] = pot[j] / 10.0f;
  }
}

// ---------------- host ----------------
extern "C" void kernel_launch(void* const* d_in, const int* in_sizes, int n_in,
                              void* d_out, int out_size, void* d_ws, size_t ws_size,
                              hipStream_t stream)
{
  const float* state = (const float*)d_in[0];
  const float* hist  = (const float*)d_in[1];
  const float* c1w   = (const float*)d_in[2];
  const float* c1b   = (const float*)d_in[3];
  const float* c2w   = (const float*)d_in[4];
  const float* c2b   = (const float*)d_in[5];
  const float* c3w   = (const float*)d_in[6];
  const float* c3b   = (const float*)d_in[7];
  const float* f1w   = (const float*)d_in[8];
  const float* f1b   = (const float*)d_in[9];
  const float* f2w   = (const float*)d_in[10];
  const float* f2b   = (const float*)d_in[11];
  const float* f3w   = (const float*)d_in[12];
  const float* f3b   = (const float*)d_in[13];
  float* out = (float*)d_out;
  float* ws  = (float*)d_ws;

  // workspace layout (floats), with aliasing:
  // region A [0 .. 24,780,800): conv1out; later feats [0..9,437,184) + wT1 [9,437,184..14,167,296)
  // region B [24,780,800 ..): conv2out (11,079,680); later h1part (1,048,576) + h1 (32768) + wT2 (32768)
  float* conv1out = ws;
  float* feats    = ws;
  float* wT1      = ws + 9437184;
  float* conv2out = ws + 24780800;
  float* h1part   = ws + 24780800;
  float* h1buf    = ws + 24780800 + 1048576;
  float* wT2      = ws + 24780800 + 1048576 + 32768;

  conv1_ker<<<dim3(12, 256), 256, 0, stream>>>(state, c1w, c1b, conv1out);
  conv2_ker<<<dim3(4, 256), 256, 0, stream>>>(conv1out, c2w, c2b, conv2out);
  // conv1out dead now -> safe to overwrite its tail with wT1
  transpose_fc1<<<dim3(1155), 256, 0, stream>>>(f1w, wT1);
  conv3_ker<<<dim3(4, 256), 256, 0, stream>>>(conv2out, c3w, c3b, feats);
  // conv2out dead now -> reuse region B
  transpose_fc2<<<dim3(128), 256, 0, stream>>>(f2w, wT2);
  fc1_ker<<<dim3(32, 8), 256, 0, stream>>>(feats, hist, wT1, h1part);
  fc1_reduce<<<dim3(128), 256, 0, stream>>>(h1part, h1buf);
  snn_ker<<<dim3(256), 256, 0, stream>>>(h1buf, f1b, wT2, f2b, f3w, f3b, out);
}

// Round 5
// 783.766 us; speedup vs baseline: 1.4024x; 1.4024x over previous
//
#include <hip/hip_runtime.h>
#include <cstddef>
#include <cstdint>

#define ALPHA 0.9f
#define BETA  0.8f

// ---------------- sizes ----------------
// conv1: 32x3x8x8 s4 -> [256,32,55,55]
// conv2: 64x32x4x4 s2 -> [256,64,26,26]
// conv3: 64x64x3x3 s1 -> [256,64,24,24] -> feats 36864
// base = feats(36864) + history(90) = 36954, padded to 36960 (= 33*35*32)
#define FEAT   36864
#define HIST   90
#define K1     36954
#define KP     36960

typedef __attribute__((ext_vector_type(8))) short short8;
typedef __attribute__((ext_vector_type(4))) float f32x4;

__device__ __forceinline__ unsigned short f2bf(float x) {
  unsigned u = __float_as_uint(x);
  return (unsigned short)((u + 0x7FFFu + ((u >> 16) & 1u)) >> 16);
}
__device__ __forceinline__ float bf2f(unsigned short h) {
  return __uint_as_float(((unsigned)h) << 16);
}

// ---------------- conv1 ----------------
__global__ __launch_bounds__(256) void conv1_ker(const float* __restrict__ in,
    const float* __restrict__ w, const float* __restrict__ bias, float* __restrict__ out)
{
  __shared__ float wl[192 * 32];   // [k][cout]
  int t = threadIdx.x;
  for (int idx = t; idx < 6144; idx += 256) {
    int co = idx / 192, k = idx % 192;
    wl[k * 32 + co] = w[idx];
  }
  __syncthreads();
  int b = blockIdx.y;
  int pos = blockIdx.x * 256 + t;
  if (pos >= 55 * 55) return;
  int y = pos / 55, x = pos % 55;
  const float* ip = in + (size_t)b * 3 * 224 * 224;
  float acc[32];
#pragma unroll
  for (int q = 0; q < 32; ++q) acc[q] = 0.f;
  for (int c = 0; c < 3; ++c) {
#pragma unroll
    for (int kh = 0; kh < 8; ++kh) {
      const float* r = ip + (size_t)(c * 224 + (y * 4 + kh)) * 224 + x * 4;
      const float4 i0 = *(const float4*)(r);
      const float4 i1 = *(const float4*)(r + 4);
      float iv[8] = {i0.x, i0.y, i0.z, i0.w, i1.x, i1.y, i1.z, i1.w};
#pragma unroll
      for (int kw = 0; kw < 8; ++kw) {
        const float4* wp = (const float4*)(wl + ((c * 8 + kh) * 8 + kw) * 32);
#pragma unroll
        for (int q = 0; q < 8; ++q) {
          float4 wv = wp[q];
          acc[q * 4 + 0] += iv[kw] * wv.x;
          acc[q * 4 + 1] += iv[kw] * wv.y;
          acc[q * 4 + 2] += iv[kw] * wv.z;
          acc[q * 4 + 3] += iv[kw] * wv.w;
        }
      }
    }
  }
  size_t ob = (size_t)b * 32 * 3025 + pos;
#pragma unroll
  for (int q = 0; q < 32; ++q) {
    float v = acc[q] + bias[q];
    out[ob + (size_t)q * 3025] = v > 0.f ? v : 0.f;
  }
}

// ---------------- conv2 ----------------
__global__ __launch_bounds__(256) void conv2_ker(const float* __restrict__ in,
    const float* __restrict__ w, const float* __restrict__ bias, float* __restrict__ out)
{
  __shared__ float wl[512 * 16];   // [k][cout_local]
  int t = threadIdx.x;
  int g = blockIdx.x;   // cout group 0..3 (16 each)
  int b = blockIdx.y;
  for (int idx = t; idx < 8192; idx += 256) {
    int q = idx / 512, k = idx % 512;
    wl[k * 16 + q] = w[(size_t)(g * 16 + q) * 512 + k];
  }
  __syncthreads();
  const float* ip = in + (size_t)b * 32 * 3025;
  for (int pos = t; pos < 26 * 26; pos += 256) {
    int y = pos / 26, x = pos % 26;
    float acc[16];
#pragma unroll
    for (int q = 0; q < 16; ++q) acc[q] = 0.f;
    for (int c = 0; c < 32; ++c) {
#pragma unroll
      for (int kh = 0; kh < 4; ++kh) {
        const float* r = ip + (size_t)(c * 55 + (y * 2 + kh)) * 55 + x * 2;
#pragma unroll
        for (int kw = 0; kw < 4; ++kw) {
          float iv = r[kw];
          const float4* wp = (const float4*)(wl + ((c * 16 + kh * 4 + kw) << 4));
#pragma unroll
          for (int q = 0; q < 4; ++q) {
            float4 wv = wp[q];
            acc[q * 4 + 0] += iv * wv.x;
            acc[q * 4 + 1] += iv * wv.y;
            acc[q * 4 + 2] += iv * wv.z;
            acc[q * 4 + 3] += iv * wv.w;
          }
        }
      }
    }
    size_t ob = ((size_t)b * 64 + g * 16) * 676 + pos;
#pragma unroll
    for (int q = 0; q < 16; ++q) {
      float v = acc[q] + bias[g * 16 + q];
      out[ob + (size_t)q * 676] = v > 0.f ? v : 0.f;
    }
  }
}

// ---------------- conv3 (writes feats layout [b][c][y][x]) ----------------
__global__ __launch_bounds__(256) void conv3_ker(const float* __restrict__ in,
    const float* __restrict__ w, const float* __restrict__ bias, float* __restrict__ feats)
{
  __shared__ float wl[576 * 16];
  int t = threadIdx.x;
  int g = blockIdx.x;   // 0..3
  int b = blockIdx.y;
  for (int idx = t; idx < 9216; idx += 256) {
    int q = idx / 576, k = idx % 576;
    wl[k * 16 + q] = w[(size_t)(g * 16 + q) * 576 + k];
  }
  __syncthreads();
  const float* ip = in + (size_t)b * 64 * 676;
  for (int pos = t; pos < 24 * 24; pos += 256) {
    int y = pos / 24, x = pos % 24;
    float acc[16];
#pragma unroll
    for (int q = 0; q < 16; ++q) acc[q] = 0.f;
    for (int c = 0; c < 64; ++c) {
#pragma unroll
      for (int kh = 0; kh < 3; ++kh) {
        const float* r = ip + (size_t)(c * 26 + (y + kh)) * 26 + x;
#pragma unroll
        for (int kw = 0; kw < 3; ++kw) {
          float iv = r[kw];
          const float4* wp = (const float4*)(wl + ((c * 9 + kh * 3 + kw) << 4));
#pragma unroll
          for (int q = 0; q < 4; ++q) {
            float4 wv = wp[q];
            acc[q * 4 + 0] += iv * wv.x;
            acc[q * 4 + 1] += iv * wv.y;
            acc[q * 4 + 2] += iv * wv.z;
            acc[q * 4 + 3] += iv * wv.w;
          }
        }
      }
    }
    size_t ob = (size_t)b * FEAT + (size_t)(g * 16) * 576 + pos;
#pragma unroll
    for (int q = 0; q < 16; ++q) {
      float v = acc[q] + bias[g * 16 + q];
      feats[ob + (size_t)q * 576] = v > 0.f ? v : 0.f;
    }
  }
}

// ---- base (feats+history, zero-padded) -> bf16 hi/lo planes [256][36960] ----
__global__ __launch_bounds__(256) void convert_base(const float* __restrict__ feats,
    const float* __restrict__ hist, unsigned short* __restrict__ hi,
    unsigned short* __restrict__ lo)
{
  int b = blockIdx.y;
  int k = blockIdx.x * 256 + threadIdx.x;
  if (k >= KP) return;
  float x = 0.f;
  if (k < FEAT) x = feats[(size_t)b * FEAT + k];
  else if (k < K1) x = hist[b * HIST + (k - FEAT)];
  unsigned short h = f2bf(x);
  unsigned short l = f2bf(x - bf2f(h));
  size_t o = (size_t)b * KP + k;
  hi[o] = h; lo[o] = l;
}

// ---- fc1 weights [128][36954] -> bf16 hi/lo planes [128][36960] (zero-padded) ----
__global__ __launch_bounds__(256) void convert_w1(const float* __restrict__ w,
    unsigned short* __restrict__ hi, unsigned short* __restrict__ lo)
{
  int o = blockIdx.y;
  int k = blockIdx.x * 256 + threadIdx.x;
  if (k >= KP) return;
  float x = (k < K1) ? w[(size_t)o * K1 + k] : 0.f;
  unsigned short h = f2bf(x);
  unsigned short l = f2bf(x - bf2f(h));
  size_t p = (size_t)o * KP + k;
  hi[p] = h; lo[p] = l;
}

// ---------------- fc2 weight transpose: [256][128] -> [128][256] ----------------
__global__ __launch_bounds__(256) void transpose_fc2(const float* __restrict__ w,
                                                     float* __restrict__ wT)
{
  int idx = blockIdx.x * 256 + threadIdx.x;
  if (idx < 128 * 256) {
    int i = idx >> 8, j = idx & 255;
    wT[idx] = w[j * 128 + i];
  }
}

// ---- fc1 MFMA bf16x3 split-K: wave = 32 samples x 16 outs, KSPLIT=33, 35 K-steps ----
// A-frag (16x16x32 bf16): row = lane&15, k = (lane>>4)*8 + j  (8 contiguous bf16 = 16B)
// B-frag: col = lane&15, same k mapping. D: col = lane&15, row = (lane>>4)*4 + reg.
__global__ __launch_bounds__(256) void fc1_mfma(const unsigned short* __restrict__ bhi,
    const unsigned short* __restrict__ blo, const unsigned short* __restrict__ whi,
    const unsigned short* __restrict__ wlo, float* __restrict__ part)
{
  int w = threadIdx.x >> 6, lane = threadIdx.x & 63;
  int job = blockIdx.x * 4 + w;        // 0..63
  int mt2 = job & 7, nt = job >> 3;    // 8 x 32-sample tiles, 8 x 16-out tiles
  int ks = blockIdx.y;                 // 0..32
  int k0 = ks * 35 * 32;               // 1120 per chunk
  int l15 = lane & 15, kg = lane >> 4;
  int s0 = mt2 * 32 + l15;
  int o  = nt * 16 + l15;
  const unsigned short* pa0h = bhi + (size_t)s0 * KP + k0 + kg * 8;
  const unsigned short* pa1h = pa0h + (size_t)16 * KP;
  const unsigned short* pa0l = blo + (size_t)s0 * KP + k0 + kg * 8;
  const unsigned short* pa1l = pa0l + (size_t)16 * KP;
  const unsigned short* pbh  = whi + (size_t)o * KP + k0 + kg * 8;
  const unsigned short* pbl  = wlo + (size_t)o * KP + k0 + kg * 8;
  f32x4 acc0 = {0.f, 0.f, 0.f, 0.f}, acc1 = {0.f, 0.f, 0.f, 0.f};
#pragma unroll 1
  for (int i = 0; i < 35; ++i) {
    short8 a0h = *(const short8*)pa0h;
    short8 a1h = *(const short8*)pa1h;
    short8 a0l = *(const short8*)pa0l;
    short8 a1l = *(const short8*)pa1l;
    short8 bh  = *(const short8*)pbh;
    short8 bl  = *(const short8*)pbl;
    acc0 = __builtin_amdgcn_mfma_f32_16x16x32_bf16(a0h, bh, acc0, 0, 0, 0);
    acc1 = __builtin_amdgcn_mfma_f32_16x16x32_bf16(a1h, bh, acc1, 0, 0, 0);
    acc0 = __builtin_amdgcn_mfma_f32_16x16x32_bf16(a0h, bl, acc0, 0, 0, 0);
    acc1 = __builtin_amdgcn_mfma_f32_16x16x32_bf16(a1h, bl, acc1, 0, 0, 0);
    acc0 = __builtin_amdgcn_mfma_f32_16x16x32_bf16(a0l, bh, acc0, 0, 0, 0);
    acc1 = __builtin_amdgcn_mfma_f32_16x16x32_bf16(a1l, bh, acc1, 0, 0, 0);
    pa0h += 32; pa1h += 32; pa0l += 32; pa1l += 32; pbh += 32; pbl += 32;
  }
  float* pp0 = part + (((size_t)ks * 64 + job) * 2) * 256;
  float* pp1 = pp0 + 256;
#pragma unroll
  for (int r = 0; r < 4; ++r) {
    pp0[r * 64 + lane] = acc0[r];
    pp1[r * 64 + lane] = acc1[r];
  }
}

// ---- fixed-order split-K reduce: h1[s][o] = sum_ks part ----
__global__ __launch_bounds__(256) void fc1_reduce(const float* __restrict__ part,
                                                  float* __restrict__ h1)
{
  int i = blockIdx.x * 256 + threadIdx.x;   // 0..32767
  if (i >= 32768) return;
  int s = i >> 7, o = i & 127;
  int mt2 = s >> 5, ti = (s >> 4) & 1, nt = o >> 4;
  int job = nt * 8 + mt2;
  int r = s & 15, c = o & 15;
  int off = (job * 2 + ti) * 256 + (r & 3) * 64 + ((r >> 2) << 4) + c;
  float sum = 0.f;
#pragma unroll 1
  for (int ks = 0; ks < 33; ++ks) sum += part[(size_t)ks * 32768 + off];
  h1[i] = sum;
}

// ---------------- SNN simulation: one block per sample ----------------
__global__ __launch_bounds__(256) void snn_ker(const float* __restrict__ h1,
    const float* __restrict__ b1, const float* __restrict__ w2T,
    const float* __restrict__ b2p, const float* __restrict__ w3,
    const float* __restrict__ b3p, float* __restrict__ out)
{
  int b = blockIdx.x, t = threadIdx.x;
  __shared__ float spk1l[128];
  __shared__ float part[4][9];
  float h1v = 0.f;
  if (t < 128) h1v = h1[b * 128 + t] + b1[t];
  float b2 = b2p[t];
  float w3r[9];
#pragma unroll
  for (int j = 0; j < 9; ++j) w3r[j] = w3[j * 256 + t];
  float mem1 = 0.f, syn1 = 0.f, mem2 = 0.f, syn2 = 0.f;
  float syn3[9], mem3[9], pot[9];
#pragma unroll
  for (int j = 0; j < 9; ++j) { syn3[j] = 0.f; mem3[j] = 0.f; pot[j] = 0.f; }

#pragma unroll 1
  for (int step = 0; step < 10; ++step) {
    if (t < 128) {
      syn1 = ALPHA * syn1 + h1v;
      mem1 = BETA * mem1 + syn1;
      float s = (mem1 > 1.0f) ? 1.f : 0.f;
      spk1l[t] = s;
      mem1 -= s;
    }
    __syncthreads();
    float h2 = b2;
    for (int i = 0; i < 128; ++i) {
      if (spk1l[i] != 0.f) h2 += w2T[i * 256 + t];
    }
    syn2 = ALPHA * syn2 + h2;
    mem2 = BETA * mem2 + syn2;
    float s2 = (mem2 > 1.0f) ? 1.f : 0.f;
    mem2 -= s2;

    float v[9];
#pragma unroll
    for (int j = 0; j < 9; ++j) v[j] = s2 * w3r[j];
#pragma unroll
    for (int j = 0; j < 9; ++j) {
      v[j] += __shfl_down(v[j], 32);
      v[j] += __shfl_down(v[j], 16);
      v[j] += __shfl_down(v[j], 8);
      v[j] += __shfl_down(v[j], 4);
      v[j] += __shfl_down(v[j], 2);
      v[j] += __shfl_down(v[j], 1);
    }
    if ((t & 63) == 0) {
#pragma unroll
      for (int j = 0; j < 9; ++j) part[t >> 6][j] = v[j];
    }
    __syncthreads();
    if (t == 0) {
#pragma unroll
      for (int j = 0; j < 9; ++j) {
        float h3 = part[0][j] + part[1][j] + part[2][j] + part[3][j] + b3p[j];
        syn3[j] = ALPHA * syn3[j] + h3;
        mem3[j] = BETA * mem3[j] + syn3[j];
        pot[j] += mem3[j];
      }
    }
  }
  if (t == 0) {
#pragma unroll
    for (int j = 0; j < 9; ++j) out[b * 9 + j] = pot[j] / 10.0f;
  }
}

// ---------------- host ----------------
extern "C" void kernel_launch(void* const* d_in, const int* in_sizes, int n_in,
                              void* d_out, int out_size, void* d_ws, size_t ws_size,
                              hipStream_t stream)
{
  const float* state = (const float*)d_in[0];
  const float* hist  = (const float*)d_in[1];
  const float* c1w   = (const float*)d_in[2];
  const float* c1b   = (const float*)d_in[3];
  const float* c2w   = (const float*)d_in[4];
  const float* c2b   = (const float*)d_in[5];
  const float* c3w   = (const float*)d_in[6];
  const float* c3b   = (const float*)d_in[7];
  const float* f1w   = (const float*)d_in[8];
  const float* f1b   = (const float*)d_in[9];
  const float* f2w   = (const float*)d_in[10];
  const float* f2b   = (const float*)d_in[11];
  const float* f3w   = (const float*)d_in[12];
  const float* f3b   = (const float*)d_in[13];
  float* out = (float*)d_out;
  float* ws  = (float*)d_ws;

  // workspace layout (float offsets):
  // region A [0, 24,780,800): conv1out; after conv2: feats [0, 9,437,184),
  //   base_hi [9,437,184, 14,168,064), base_lo [14,168,064, 18,898,944),
  //   w1_hi [18,898,944, 21,264,384), w1_lo [21,264,384, 23,629,824)
  // region B [24,780,800, 35,860,480): conv2out; after conv3:
  //   part [24,780,800, 25,862,144), h1 [25,862,144, 25,894,912), wT2 [.., 25,927,680)
  float* conv1out = ws;
  float* feats    = ws;
  unsigned short* base_hi = (unsigned short*)(ws + 9437184);
  unsigned short* base_lo = (unsigned short*)(ws + 14168064);
  unsigned short* w1_hi   = (unsigned short*)(ws + 18898944);
  unsigned short* w1_lo   = (unsigned short*)(ws + 21264384);
  float* conv2out = ws + 24780800;
  float* partb    = ws + 24780800;
  float* h1buf    = ws + 25862144;
  float* wT2      = ws + 25894912;

  conv1_ker<<<dim3(12, 256), 256, 0, stream>>>(state, c1w, c1b, conv1out);
  conv2_ker<<<dim3(4, 256), 256, 0, stream>>>(conv1out, c2w, c2b, conv2out);
  // conv1out dead -> region A tail reusable
  convert_w1<<<dim3(145, 128), 256, 0, stream>>>(f1w, w1_hi, w1_lo);
  conv3_ker<<<dim3(4, 256), 256, 0, stream>>>(conv2out, c3w, c3b, feats);
  convert_base<<<dim3(145, 256), 256, 0, stream>>>(feats, hist, base_hi, base_lo);
  // conv2out dead -> region B reusable
  transpose_fc2<<<dim3(128), 256, 0, stream>>>(f2w, wT2);
  fc1_mfma<<<dim3(16, 33), 256, 0, stream>>>(base_hi, base_lo, w1_hi, w1_lo, partb);
  fc1_reduce<<<dim3(128), 256, 0, stream>>>(partb, h1buf);
  snn_ker<<<dim3(256), 256, 0, stream>>>(h1buf, f1b, wT2, f2b, f3w, f3b, out);
}

// Round 6
// 731.690 us; speedup vs baseline: 1.5022x; 1.0712x over previous
//
#include <hip/hip_runtime.h>
#include <cstddef>
#include <cstdint>

#define ALPHA 0.9f
#define BETA  0.8f

// ---------------- sizes ----------------
// conv1: 32x3x8x8 s4 -> [256,32,55,55]
// conv2: 64x32x4x4 s2 -> [256,64,26,26]  (written channels-last bf16 hi/lo)
// conv3: 64x64x3x3 s1 -> [256,64,24,24] -> feats 36864 (written as bf16 hi/lo base planes)
// base = feats(36864) + history(90) = 36954, padded to 36960 (= 33*35*32)
#define FEAT   36864
#define HIST   90
#define K1     36954
#define KP     36960

typedef __attribute__((ext_vector_type(8))) short short8;
typedef __attribute__((ext_vector_type(4))) float f32x4;

__device__ __forceinline__ unsigned short f2bf(float x) {
  unsigned u = __float_as_uint(x);
  return (unsigned short)((u + 0x7FFFu + ((u >> 16) & 1u)) >> 16);
}
__device__ __forceinline__ float bf2f(unsigned short h) {
  return __uint_as_float(((unsigned)h) << 16);
}

// ---------------- conv1 (unchanged fp32 VALU) ----------------
__global__ __launch_bounds__(256) void conv1_ker(const float* __restrict__ in,
    const float* __restrict__ w, const float* __restrict__ bias, float* __restrict__ out)
{
  __shared__ float wl[192 * 32];   // [k][cout]
  int t = threadIdx.x;
  for (int idx = t; idx < 6144; idx += 256) {
    int co = idx / 192, k = idx % 192;
    wl[k * 32 + co] = w[idx];
  }
  __syncthreads();
  int b = blockIdx.y;
  int pos = blockIdx.x * 256 + t;
  if (pos >= 55 * 55) return;
  int y = pos / 55, x = pos % 55;
  const float* ip = in + (size_t)b * 3 * 224 * 224;
  float acc[32];
#pragma unroll
  for (int q = 0; q < 32; ++q) acc[q] = 0.f;
  for (int c = 0; c < 3; ++c) {
#pragma unroll
    for (int kh = 0; kh < 8; ++kh) {
      const float* r = ip + (size_t)(c * 224 + (y * 4 + kh)) * 224 + x * 4;
      const float4 i0 = *(const float4*)(r);
      const float4 i1 = *(const float4*)(r + 4);
      float iv[8] = {i0.x, i0.y, i0.z, i0.w, i1.x, i1.y, i1.z, i1.w};
#pragma unroll
      for (int kw = 0; kw < 8; ++kw) {
        const float4* wp = (const float4*)(wl + ((c * 8 + kh) * 8 + kw) * 32);
#pragma unroll
        for (int q = 0; q < 8; ++q) {
          float4 wv = wp[q];
          acc[q * 4 + 0] += iv[kw] * wv.x;
          acc[q * 4 + 1] += iv[kw] * wv.y;
          acc[q * 4 + 2] += iv[kw] * wv.z;
          acc[q * 4 + 3] += iv[kw] * wv.w;
        }
      }
    }
  }
  size_t ob = (size_t)b * 32 * 3025 + pos;
#pragma unroll
  for (int q = 0; q < 32; ++q) {
    float v = acc[q] + bias[q];
    out[ob + (size_t)q * 3025] = v > 0.f ? v : 0.f;
  }
}

// ------- conv2: fp32 VALU compute, epilogue writes channels-last bf16 hi/lo -------
// output layout: [b][pos=y*26+x][cin=64] for each plane
__global__ __launch_bounds__(256) void conv2_ker(const float* __restrict__ in,
    const float* __restrict__ w, const float* __restrict__ bias,
    unsigned short* __restrict__ ohi, unsigned short* __restrict__ olo)
{
  __shared__ float wl[512 * 16];   // [k][cout_local]
  int t = threadIdx.x;
  int g = blockIdx.x;   // cout group 0..3 (16 each)
  int b = blockIdx.y;
  for (int idx = t; idx < 8192; idx += 256) {
    int q = idx / 512, k = idx % 512;
    wl[k * 16 + q] = w[(size_t)(g * 16 + q) * 512 + k];
  }
  __syncthreads();
  const float* ip = in + (size_t)b * 32 * 3025;
  for (int pos = t; pos < 26 * 26; pos += 256) {
    int y = pos / 26, x = pos % 26;
    float acc[16];
#pragma unroll
    for (int q = 0; q < 16; ++q) acc[q] = 0.f;
    for (int c = 0; c < 32; ++c) {
#pragma unroll
      for (int kh = 0; kh < 4; ++kh) {
        const float* r = ip + (size_t)(c * 55 + (y * 2 + kh)) * 55 + x * 2;
#pragma unroll
        for (int kw = 0; kw < 4; ++kw) {
          float iv = r[kw];
          const float4* wp = (const float4*)(wl + ((c * 16 + kh * 4 + kw) << 4));
#pragma unroll
          for (int q = 0; q < 4; ++q) {
            float4 wv = wp[q];
            acc[q * 4 + 0] += iv * wv.x;
            acc[q * 4 + 1] += iv * wv.y;
            acc[q * 4 + 2] += iv * wv.z;
            acc[q * 4 + 3] += iv * wv.w;
          }
        }
      }
    }
    size_t ob = ((size_t)b * 676 + pos) * 64 + g * 16;
    short8 h0, h1v, l0, l1v;
#pragma unroll
    for (int q = 0; q < 8; ++q) {
      float v = acc[q] + bias[g * 16 + q];
      v = v > 0.f ? v : 0.f;
      unsigned short hh = f2bf(v);
      h0[q] = (short)hh; l0[q] = (short)f2bf(v - bf2f(hh));
    }
#pragma unroll
    for (int q = 0; q < 8; ++q) {
      float v = acc[8 + q] + bias[g * 16 + 8 + q];
      v = v > 0.f ? v : 0.f;
      unsigned short hh = f2bf(v);
      h1v[q] = (short)hh; l1v[q] = (short)f2bf(v - bf2f(hh));
    }
    *(short8*)(ohi + ob) = h0;  *(short8*)(ohi + ob + 8) = h1v;
    *(short8*)(olo + ob) = l0;  *(short8*)(olo + ob + 8) = l1v;
  }
}

// ---- conv3 weights [cout][cin][3][3] fp32 -> [tap][cout][cin] bf16 hi/lo ----
__global__ __launch_bounds__(256) void convert_w3(const float* __restrict__ w,
    unsigned short* __restrict__ hi, unsigned short* __restrict__ lo)
{
  int i = blockIdx.x * 256 + threadIdx.x;   // dst index
  if (i >= 9 * 64 * 64) return;
  int tap = i >> 12, rem = i & 4095;
  int cout = rem >> 6, cin = rem & 63;
  float x = w[cout * 576 + cin * 9 + tap];
  unsigned short h = f2bf(x);
  hi[i] = h; lo[i] = f2bf(x - bf2f(h));
}

// ---- conv3 implicit-GEMM MFMA bf16x3: per batch, M=576 pos, N=64 cout, K=64 cin x 9 taps
// wave: 32 pos x 32 cout (2x2 fragments). Writes base_hi/lo planes [b][cout*576+pos].
__global__ __launch_bounds__(256) void conv3_mfma(const unsigned short* __restrict__ xhi,
    const unsigned short* __restrict__ xlo, const unsigned short* __restrict__ whi,
    const unsigned short* __restrict__ wlo, const float* __restrict__ bias,
    unsigned short* __restrict__ bhi, unsigned short* __restrict__ blo)
{
  int wv = threadIdx.x >> 6, lane = threadIdx.x & 63;
  int b = blockIdx.y;
  int job = blockIdx.x * 4 + wv;      // 0..35
  int mpair = job >> 1, npair = job & 1;
  int l15 = lane & 15, kg = lane >> 4;
  // A rows (two 16-row tiles)
  int pos0 = mpair * 32 + l15;
  int pos1 = pos0 + 16;
  int y0 = pos0 / 24, x0 = pos0 % 24;
  int y1 = pos1 / 24, x1 = pos1 % 24;
  size_t boff = (size_t)b * 43264;    // 26*26*64
  int ia0 = (y0 * 26 + x0) * 64 + kg * 8;
  int ia1 = (y1 * 26 + x1) * 64 + kg * 8;
  // B cols (two 16-cout tiles)
  int co0 = npair * 32 + l15;
  int co1 = co0 + 16;
  int ib0 = co0 * 64 + kg * 8;
  int ib1 = co1 * 64 + kg * 8;
  f32x4 a00 = {0,0,0,0}, a01 = {0,0,0,0}, a10 = {0,0,0,0}, a11 = {0,0,0,0};
#pragma unroll 3
  for (int tap = 0; tap < 9; ++tap) {
    int kh = tap / 3, kw = tap % 3;
    int toff = (kh * 26 + kw) * 64;
    int wboff = tap * 4096;
#pragma unroll
    for (int ks = 0; ks < 2; ++ks) {
      int ko = ks * 32;
      short8 A0h = *(const short8*)(xhi + boff + ia0 + toff + ko);
      short8 A0l = *(const short8*)(xlo + boff + ia0 + toff + ko);
      short8 A1h = *(const short8*)(xhi + boff + ia1 + toff + ko);
      short8 A1l = *(const short8*)(xlo + boff + ia1 + toff + ko);
      short8 B0h = *(const short8*)(whi + wboff + ib0 + ko);
      short8 B0l = *(const short8*)(wlo + wboff + ib0 + ko);
      short8 B1h = *(const short8*)(whi + wboff + ib1 + ko);
      short8 B1l = *(const short8*)(wlo + wboff + ib1 + ko);
      a00 = __builtin_amdgcn_mfma_f32_16x16x32_bf16(A0h, B0h, a00, 0, 0, 0);
      a01 = __builtin_amdgcn_mfma_f32_16x16x32_bf16(A0h, B1h, a01, 0, 0, 0);
      a10 = __builtin_amdgcn_mfma_f32_16x16x32_bf16(A1h, B0h, a10, 0, 0, 0);
      a11 = __builtin_amdgcn_mfma_f32_16x16x32_bf16(A1h, B1h, a11, 0, 0, 0);
      a00 = __builtin_amdgcn_mfma_f32_16x16x32_bf16(A0h, B0l, a00, 0, 0, 0);
      a01 = __builtin_amdgcn_mfma_f32_16x16x32_bf16(A0h, B1l, a01, 0, 0, 0);
      a10 = __builtin_amdgcn_mfma_f32_16x16x32_bf16(A1h, B0l, a10, 0, 0, 0);
      a11 = __builtin_amdgcn_mfma_f32_16x16x32_bf16(A1h, B1l, a11, 0, 0, 0);
      a00 = __builtin_amdgcn_mfma_f32_16x16x32_bf16(A0l, B0h, a00, 0, 0, 0);
      a01 = __builtin_amdgcn_mfma_f32_16x16x32_bf16(A0l, B1h, a01, 0, 0, 0);
      a10 = __builtin_amdgcn_mfma_f32_16x16x32_bf16(A1l, B0h, a10, 0, 0, 0);
      a11 = __builtin_amdgcn_mfma_f32_16x16x32_bf16(A1l, B1h, a11, 0, 0, 0);
    }
  }
  // epilogue: D row = kg*4 + r (pos within 16-tile), col = l15 (cout within tile)
  float bia0 = bias[co0], bia1 = bias[co1];
  size_t ob = (size_t)b * KP;
#pragma unroll
  for (int r = 0; r < 4; ++r) {
    int p0 = mpair * 32 + kg * 4 + r;        // tile m0 row
    int p1 = p0 + 16;                        // tile m1 row
    float v; unsigned short h;
    v = a00[r] + bia0; v = v > 0.f ? v : 0.f; h = f2bf(v);
    bhi[ob + (size_t)co0 * 576 + p0] = h; blo[ob + (size_t)co0 * 576 + p0] = f2bf(v - bf2f(h));
    v = a01[r] + bia1; v = v > 0.f ? v : 0.f; h = f2bf(v);
    bhi[ob + (size_t)co1 * 576 + p0] = h; blo[ob + (size_t)co1 * 576 + p0] = f2bf(v - bf2f(h));
    v = a10[r] + bia0; v = v > 0.f ? v : 0.f; h = f2bf(v);
    bhi[ob + (size_t)co0 * 576 + p1] = h; blo[ob + (size_t)co0 * 576 + p1] = f2bf(v - bf2f(h));
    v = a11[r] + bia1; v = v > 0.f ? v : 0.f; h = f2bf(v);
    bhi[ob + (size_t)co1 * 576 + p1] = h; blo[ob + (size_t)co1 * 576 + p1] = f2bf(v - bf2f(h));
  }
}

// ---- fill history tail + zero pad of base planes: k in [36864, 36960) ----
__global__ __launch_bounds__(128) void fill_hist(const float* __restrict__ hist,
    unsigned short* __restrict__ bhi, unsigned short* __restrict__ blo)
{
  int b = blockIdx.x, t = threadIdx.x;
  int k = FEAT + t;
  if (k >= KP) return;
  float x = (k < K1) ? hist[b * HIST + t] : 0.f;
  unsigned short h = f2bf(x);
  size_t o = (size_t)b * KP + k;
  bhi[o] = h; blo[o] = f2bf(x - bf2f(h));
}

// ---- fc1 weights [128][36954] -> bf16 hi/lo planes [128][36960] (zero-padded) ----
__global__ __launch_bounds__(256) void convert_w1(const float* __restrict__ w,
    unsigned short* __restrict__ hi, unsigned short* __restrict__ lo)
{
  int o = blockIdx.y;
  int k = blockIdx.x * 256 + threadIdx.x;
  if (k >= KP) return;
  float x = (k < K1) ? w[(size_t)o * K1 + k] : 0.f;
  unsigned short h = f2bf(x);
  unsigned short l = f2bf(x - bf2f(h));
  size_t p = (size_t)o * KP + k;
  hi[p] = h; lo[p] = l;
}

// ---------------- fc2 weight transpose: [256][128] -> [128][256] ----------------
__global__ __launch_bounds__(256) void transpose_fc2(const float* __restrict__ w,
                                                     float* __restrict__ wT)
{
  int idx = blockIdx.x * 256 + threadIdx.x;
  if (idx < 128 * 256) {
    int i = idx >> 8, j = idx & 255;
    wT[idx] = w[j * 128 + i];
  }
}

// ---- fc1 MFMA bf16x3 split-K: wave = 32 samples x 16 outs, KSPLIT=33, 35 K-steps ----
__global__ __launch_bounds__(256) void fc1_mfma(const unsigned short* __restrict__ bhi,
    const unsigned short* __restrict__ blo, const unsigned short* __restrict__ whi,
    const unsigned short* __restrict__ wlo, float* __restrict__ part)
{
  int w = threadIdx.x >> 6, lane = threadIdx.x & 63;
  int job = blockIdx.x * 4 + w;        // 0..63
  int mt2 = job & 7, nt = job >> 3;    // 8 x 32-sample tiles, 8 x 16-out tiles
  int ks = blockIdx.y;                 // 0..32
  int k0 = ks * 35 * 32;               // 1120 per chunk
  int l15 = lane & 15, kg = lane >> 4;
  int s0 = mt2 * 32 + l15;
  int o  = nt * 16 + l15;
  const unsigned short* pa0h = bhi + (size_t)s0 * KP + k0 + kg * 8;
  const unsigned short* pa1h = pa0h + (size_t)16 * KP;
  const unsigned short* pa0l = blo + (size_t)s0 * KP + k0 + kg * 8;
  const unsigned short* pa1l = pa0l + (size_t)16 * KP;
  const unsigned short* pbh  = whi + (size_t)o * KP + k0 + kg * 8;
  const unsigned short* pbl  = wlo + (size_t)o * KP + k0 + kg * 8;
  f32x4 acc0 = {0.f, 0.f, 0.f, 0.f}, acc1 = {0.f, 0.f, 0.f, 0.f};
#pragma unroll 1
  for (int i = 0; i < 35; ++i) {
    short8 a0h = *(const short8*)pa0h;
    short8 a1h = *(const short8*)pa1h;
    short8 a0l = *(const short8*)pa0l;
    short8 a1l = *(const short8*)pa1l;
    short8 bh  = *(const short8*)pbh;
    short8 bl  = *(const short8*)pbl;
    acc0 = __builtin_amdgcn_mfma_f32_16x16x32_bf16(a0h, bh, acc0, 0, 0, 0);
    acc1 = __builtin_amdgcn_mfma_f32_16x16x32_bf16(a1h, bh, acc1, 0, 0, 0);
    acc0 = __builtin_amdgcn_mfma_f32_16x16x32_bf16(a0h, bl, acc0, 0, 0, 0);
    acc1 = __builtin_amdgcn_mfma_f32_16x16x32_bf16(a1h, bl, acc1, 0, 0, 0);
    acc0 = __builtin_amdgcn_mfma_f32_16x16x32_bf16(a0l, bh, acc0, 0, 0, 0);
    acc1 = __builtin_amdgcn_mfma_f32_16x16x32_bf16(a1l, bh, acc1, 0, 0, 0);
    pa0h += 32; pa1h += 32; pa0l += 32; pa1l += 32; pbh += 32; pbl += 32;
  }
  float* pp0 = part + (((size_t)ks * 64 + job) * 2) * 256;
  float* pp1 = pp0 + 256;
#pragma unroll
  for (int r = 0; r < 4; ++r) {
    pp0[r * 64 + lane] = acc0[r];
    pp1[r * 64 + lane] = acc1[r];
  }
}

// ---- fixed-order split-K reduce ----
__global__ __launch_bounds__(256) void fc1_reduce(const float* __restrict__ part,
                                                  float* __restrict__ h1)
{
  int i = blockIdx.x * 256 + threadIdx.x;   // 0..32767
  if (i >= 32768) return;
  int s = i >> 7, o = i & 127;
  int mt2 = s >> 5, ti = (s >> 4) & 1, nt = o >> 4;
  int job = nt * 8 + mt2;
  int r = s & 15, c = o & 15;
  int off = (job * 2 + ti) * 256 + (r & 3) * 64 + ((r >> 2) << 4) + c;
  float sum = 0.f;
#pragma unroll 1
  for (int ks = 0; ks < 33; ++ks) sum += part[(size_t)ks * 32768 + off];
  h1[i] = sum;
}

// ---------------- SNN simulation: one block per sample ----------------
__global__ __launch_bounds__(256) void snn_ker(const float* __restrict__ h1,
    const float* __restrict__ b1, const float* __restrict__ w2T,
    const float* __restrict__ b2p, const float* __restrict__ w3,
    const float* __restrict__ b3p, float* __restrict__ out)
{
  int b = blockIdx.x, t = threadIdx.x;
  __shared__ float spk1l[128];
  __shared__ float part[4][9];
  float h1v = 0.f;
  if (t < 128) h1v = h1[b * 128 + t] + b1[t];
  float b2 = b2p[t];
  float w3r[9];
#pragma unroll
  for (int j = 0; j < 9; ++j) w3r[j] = w3[j * 256 + t];
  float mem1 = 0.f, syn1 = 0.f, mem2 = 0.f, syn2 = 0.f;
  float syn3[9], mem3[9], pot[9];
#pragma unroll
  for (int j = 0; j < 9; ++j) { syn3[j] = 0.f; mem3[j] = 0.f; pot[j] = 0.f; }

#pragma unroll 1
  for (int step = 0; step < 10; ++step) {
    if (t < 128) {
      syn1 = ALPHA * syn1 + h1v;
      mem1 = BETA * mem1 + syn1;
      float s = (mem1 > 1.0f) ? 1.f : 0.f;
      spk1l[t] = s;
      mem1 -= s;
    }
    __syncthreads();
    float h2 = b2;
    for (int i = 0; i < 128; ++i) {
      if (spk1l[i] != 0.f) h2 += w2T[i * 256 + t];
    }
    syn2 = ALPHA * syn2 + h2;
    mem2 = BETA * mem2 + syn2;
    float s2 = (mem2 > 1.0f) ? 1.f : 0.f;
    mem2 -= s2;

    float v[9];
#pragma unroll
    for (int j = 0; j < 9; ++j) v[j] = s2 * w3r[j];
#pragma unroll
    for (int j = 0; j < 9; ++j) {
      v[j] += __shfl_down(v[j], 32);
      v[j] += __shfl_down(v[j], 16);
      v[j] += __shfl_down(v[j], 8);
      v[j] += __shfl_down(v[j], 4);
      v[j] += __shfl_down(v[j], 2);
      v[j] += __shfl_down(v[j], 1);
    }
    if ((t & 63) == 0) {
#pragma unroll
      for (int j = 0; j < 9; ++j) part[t >> 6][j] = v[j];
    }
    __syncthreads();
    if (t == 0) {
#pragma unroll
      for (int j = 0; j < 9; ++j) {
        float h3 = part[0][j] + part[1][j] + part[2][j] + part[3][j] + b3p[j];
        syn3[j] = ALPHA * syn3[j] + h3;
        mem3[j] = BETA * mem3[j] + syn3[j];
        pot[j] += mem3[j];
      }
    }
  }
  if (t == 0) {
#pragma unroll
    for (int j = 0; j < 9; ++j) out[b * 9 + j] = pot[j] / 10.0f;
  }
}

// ---------------- host ----------------
extern "C" void kernel_launch(void* const* d_in, const int* in_sizes, int n_in,
                              void* d_out, int out_size, void* d_ws, size_t ws_size,
                              hipStream_t stream)
{
  const float* state = (const float*)d_in[0];
  const float* hist  = (const float*)d_in[1];
  const float* c1w   = (const float*)d_in[2];
  const float* c1b   = (const float*)d_in[3];
  const float* c2w   = (const float*)d_in[4];
  const float* c2b   = (const float*)d_in[5];
  const float* c3w   = (const float*)d_in[6];
  const float* c3b   = (const float*)d_in[7];
  const float* f1w   = (const float*)d_in[8];
  const float* f1b   = (const float*)d_in[9];
  const float* f2w   = (const float*)d_in[10];
  const float* f2b   = (const float*)d_in[11];
  const float* f3w   = (const float*)d_in[12];
  const float* f3b   = (const float*)d_in[13];
  float* out = (float*)d_out;
  float* ws  = (float*)d_ws;

  // workspace (float offsets):
  // region A [0, 24,780,800): conv1out; after conv2 it is reused as:
  //   base_hi [0, 4,730,880) base_lo [4,730,880, 9,461,760)
  //   w1_hi [9,461,760, 11,827,200) w1_lo [11,827,200, 14,192,640)
  //   w3_hi [14,192,640, 14,211,072) w3_lo [14,211,072, 14,229,504)
  //   partb [14,229,504, 15,310,848) h1 [15,310,848, ..) wT2 [15,343,616, ..)
  // region B [24,780,800, 35,856,384): c2hi, c2lo (channels-last bf16 planes)
  float* conv1out = ws;
  unsigned short* base_hi = (unsigned short*)(ws);
  unsigned short* base_lo = (unsigned short*)(ws + 4730880);
  unsigned short* w1_hi   = (unsigned short*)(ws + 9461760);
  unsigned short* w1_lo   = (unsigned short*)(ws + 11827200);
  unsigned short* w3_hi   = (unsigned short*)(ws + 14192640);
  unsigned short* w3_lo   = (unsigned short*)(ws + 14211072);
  float* partb    = ws + 14229504;
  float* h1buf    = ws + 15310848;
  float* wT2      = ws + 15343616;
  unsigned short* c2hi = (unsigned short*)(ws + 24780800);
  unsigned short* c2lo = (unsigned short*)(ws + 30318592);

  conv1_ker<<<dim3(12, 256), 256, 0, stream>>>(state, c1w, c1b, conv1out);
  conv2_ker<<<dim3(4, 256), 256, 0, stream>>>(conv1out, c2w, c2b, c2hi, c2lo);
  // conv1out dead -> region A reusable
  convert_w1<<<dim3(145, 128), 256, 0, stream>>>(f1w, w1_hi, w1_lo);
  convert_w3<<<dim3(144), 256, 0, stream>>>(c3w, w3_hi, w3_lo);
  fill_hist<<<dim3(256), 128, 0, stream>>>(hist, base_hi, base_lo);
  conv3_mfma<<<dim3(9, 256), 256, 0, stream>>>(c2hi, c2lo, w3_hi, w3_lo, c3b,
                                               base_hi, base_lo);
  transpose_fc2<<<dim3(128), 256, 0, stream>>>(f2w, wT2);
  fc1_mfma<<<dim3(16, 33), 256, 0, stream>>>(base_hi, base_lo, w1_hi, w1_lo, partb);
  fc1_reduce<<<dim3(128), 256, 0, stream>>>(partb, h1buf);
  snn_ker<<<dim3(256), 256, 0, stream>>>(h1buf, f1b, wT2, f2b, f3w, f3b, out);
}

// Round 7
// 714.040 us; speedup vs baseline: 1.5393x; 1.0247x over previous
//
#include <hip/hip_runtime.h>
#include <cstddef>
#include <cstdint>

#define ALPHA 0.9f
#define BETA  0.8f

// ---------------- sizes ----------------
// conv1: 32x3x8x8 s4 -> [256,32,55,55]   (channels-last bf16 hi/lo, two half-batch passes)
// conv2: 64x32x4x4 s2 -> [256,64,26,26]  (MFMA implicit GEMM, channels-last bf16 hi/lo)
// conv3: 64x64x3x3 s1 -> [256,64,24,24]  (MFMA implicit GEMM -> base planes)
// base = feats(36864) + history(90) = 36954, padded to 36960 (= 33*35*32)
#define FEAT   36864
#define HIST   90
#define K1     36954
#define KP     36960

typedef __attribute__((ext_vector_type(8))) short short8;
typedef __attribute__((ext_vector_type(4))) float f32x4;

__device__ __forceinline__ unsigned short f2bf(float x) {
  unsigned u = __float_as_uint(x);
  return (unsigned short)((u + 0x7FFFu + ((u >> 16) & 1u)) >> 16);
}
__device__ __forceinline__ float bf2f(unsigned short h) {
  return __uint_as_float(((unsigned)h) << 16);
}

// ------- conv1: fp32 VALU, epilogue writes channels-last bf16 hi/lo [lb][pos][32] -------
__global__ __launch_bounds__(256) void conv1_ker(const float* __restrict__ in,
    const float* __restrict__ w, const float* __restrict__ bias,
    unsigned short* __restrict__ ohi, unsigned short* __restrict__ olo, int batch0)
{
  __shared__ float wl[192 * 32];   // [k][cout]
  int t = threadIdx.x;
  for (int idx = t; idx < 6144; idx += 256) {
    int co = idx / 192, k = idx % 192;
    wl[k * 32 + co] = w[idx];
  }
  __syncthreads();
  int b = blockIdx.y;              // local batch 0..127
  int pos = blockIdx.x * 256 + t;
  if (pos >= 55 * 55) return;
  int y = pos / 55, x = pos % 55;
  const float* ip = in + (size_t)(batch0 + b) * 3 * 224 * 224;
  float acc[32];
#pragma unroll
  for (int q = 0; q < 32; ++q) acc[q] = 0.f;
  for (int c = 0; c < 3; ++c) {
#pragma unroll
    for (int kh = 0; kh < 8; ++kh) {
      const float* r = ip + (size_t)(c * 224 + (y * 4 + kh)) * 224 + x * 4;
      const float4 i0 = *(const float4*)(r);
      const float4 i1 = *(const float4*)(r + 4);
      float iv[8] = {i0.x, i0.y, i0.z, i0.w, i1.x, i1.y, i1.z, i1.w};
#pragma unroll
      for (int kw = 0; kw < 8; ++kw) {
        const float4* wp = (const float4*)(wl + ((c * 8 + kh) * 8 + kw) * 32);
#pragma unroll
        for (int q = 0; q < 8; ++q) {
          float4 wv = wp[q];
          acc[q * 4 + 0] += iv[kw] * wv.x;
          acc[q * 4 + 1] += iv[kw] * wv.y;
          acc[q * 4 + 2] += iv[kw] * wv.z;
          acc[q * 4 + 3] += iv[kw] * wv.w;
        }
      }
    }
  }
  size_t ob = ((size_t)b * 3025 + pos) * 32;
#pragma unroll
  for (int g = 0; g < 4; ++g) {
    short8 hv, lv;
#pragma unroll
    for (int q = 0; q < 8; ++q) {
      float v = acc[g * 8 + q] + bias[g * 8 + q];
      v = v > 0.f ? v : 0.f;
      unsigned short hh = f2bf(v);
      hv[q] = (short)hh; lv[q] = (short)f2bf(v - bf2f(hh));
    }
    *(short8*)(ohi + ob + g * 8) = hv;
    *(short8*)(olo + ob + g * 8) = lv;
  }
}

// ---- conv2 weights [64][32][4][4] fp32 -> [tap][cout][cin] bf16 hi/lo ----
__global__ __launch_bounds__(256) void convert_w2(const float* __restrict__ w,
    unsigned short* __restrict__ hi, unsigned short* __restrict__ lo)
{
  int i = blockIdx.x * 256 + threadIdx.x;
  if (i >= 16 * 64 * 32) return;
  int tap = i >> 11, rem = i & 2047;
  int co = rem >> 5, ci = rem & 31;
  float x = w[co * 512 + ci * 16 + tap];
  unsigned short h = f2bf(x);
  hi[i] = h; lo[i] = f2bf(x - bf2f(h));
}

// ---- conv2 implicit-GEMM MFMA bf16x3: M=676 pos (22x32 padded), N=64 cout, 16 taps x K=32 cin
// wave: 32 pos x 32 cout. input c1 planes [lb][55*55][32]; output c2 planes [B][676][64].
__global__ __launch_bounds__(256) void conv2_mfma(const unsigned short* __restrict__ xhi,
    const unsigned short* __restrict__ xlo, const unsigned short* __restrict__ whi,
    const unsigned short* __restrict__ wlo, const float* __restrict__ bias,
    unsigned short* __restrict__ ohi, unsigned short* __restrict__ olo, int batch0)
{
  int wv = threadIdx.x >> 6, lane = threadIdx.x & 63;
  int b = blockIdx.y;                 // local batch 0..127
  int job = blockIdx.x * 4 + wv;      // 0..43
  int mpair = job >> 1, npair = job & 1;
  int l15 = lane & 15, kg = lane >> 4;
  int pos0 = mpair * 32 + l15;
  int pos1 = pos0 + 16;
  int cp0 = pos0 > 675 ? 675 : pos0;
  int cp1 = pos1 > 675 ? 675 : pos1;
  int y0 = cp0 / 26, x0 = cp0 % 26;
  int y1 = cp1 / 26, x1 = cp1 % 26;
  size_t ibase = (size_t)b * 96800;   // 3025*32
  int co0 = npair * 32 + l15;
  int co1 = co0 + 16;
  int ib0 = co0 * 32 + kg * 8;
  int ib1 = co1 * 32 + kg * 8;
  f32x4 a00 = {0,0,0,0}, a01 = {0,0,0,0}, a10 = {0,0,0,0}, a11 = {0,0,0,0};
#pragma unroll 4
  for (int tap = 0; tap < 16; ++tap) {
    int kh = tap >> 2, kw = tap & 3;
    int ia0 = ((2 * y0 + kh) * 55 + 2 * x0 + kw) * 32 + kg * 8;
    int ia1 = ((2 * y1 + kh) * 55 + 2 * x1 + kw) * 32 + kg * 8;
    int wb = tap * 2048;
    short8 A0h = *(const short8*)(xhi + ibase + ia0);
    short8 A0l = *(const short8*)(xlo + ibase + ia0);
    short8 A1h = *(const short8*)(xhi + ibase + ia1);
    short8 A1l = *(const short8*)(xlo + ibase + ia1);
    short8 B0h = *(const short8*)(whi + wb + ib0);
    short8 B0l = *(const short8*)(wlo + wb + ib0);
    short8 B1h = *(const short8*)(whi + wb + ib1);
    short8 B1l = *(const short8*)(wlo + wb + ib1);
    a00 = __builtin_amdgcn_mfma_f32_16x16x32_bf16(A0h, B0h, a00, 0, 0, 0);
    a01 = __builtin_amdgcn_mfma_f32_16x16x32_bf16(A0h, B1h, a01, 0, 0, 0);
    a10 = __builtin_amdgcn_mfma_f32_16x16x32_bf16(A1h, B0h, a10, 0, 0, 0);
    a11 = __builtin_amdgcn_mfma_f32_16x16x32_bf16(A1h, B1h, a11, 0, 0, 0);
    a00 = __builtin_amdgcn_mfma_f32_16x16x32_bf16(A0h, B0l, a00, 0, 0, 0);
    a01 = __builtin_amdgcn_mfma_f32_16x16x32_bf16(A0h, B1l, a01, 0, 0, 0);
    a10 = __builtin_amdgcn_mfma_f32_16x16x32_bf16(A1h, B0l, a10, 0, 0, 0);
    a11 = __builtin_amdgcn_mfma_f32_16x16x32_bf16(A1h, B1l, a11, 0, 0, 0);
    a00 = __builtin_amdgcn_mfma_f32_16x16x32_bf16(A0l, B0h, a00, 0, 0, 0);
    a01 = __builtin_amdgcn_mfma_f32_16x16x32_bf16(A0l, B1h, a01, 0, 0, 0);
    a10 = __builtin_amdgcn_mfma_f32_16x16x32_bf16(A1l, B0h, a10, 0, 0, 0);
    a11 = __builtin_amdgcn_mfma_f32_16x16x32_bf16(A1l, B1h, a11, 0, 0, 0);
  }
  float bia0 = bias[co0], bia1 = bias[co1];
  size_t obase = (size_t)(batch0 + b) * 676;
#pragma unroll
  for (int r = 0; r < 4; ++r) {
    int p0 = mpair * 32 + kg * 4 + r;
    int p1 = p0 + 16;
    float v; unsigned short h;
    if (p0 < 676) {
      size_t o = (obase + p0) * 64;
      v = a00[r] + bia0; v = v > 0.f ? v : 0.f; h = f2bf(v);
      ohi[o + co0] = h; olo[o + co0] = f2bf(v - bf2f(h));
      v = a01[r] + bia1; v = v > 0.f ? v : 0.f; h = f2bf(v);
      ohi[o + co1] = h; olo[o + co1] = f2bf(v - bf2f(h));
    }
    if (p1 < 676) {
      size_t o = (obase + p1) * 64;
      v = a10[r] + bia0; v = v > 0.f ? v : 0.f; h = f2bf(v);
      ohi[o + co0] = h; olo[o + co0] = f2bf(v - bf2f(h));
      v = a11[r] + bia1; v = v > 0.f ? v : 0.f; h = f2bf(v);
      ohi[o + co1] = h; olo[o + co1] = f2bf(v - bf2f(h));
    }
  }
}

// ---- conv3 weights [cout][cin][3][3] fp32 -> [tap][cout][cin] bf16 hi/lo ----
__global__ __launch_bounds__(256) void convert_w3(const float* __restrict__ w,
    unsigned short* __restrict__ hi, unsigned short* __restrict__ lo)
{
  int i = blockIdx.x * 256 + threadIdx.x;
  if (i >= 9 * 64 * 64) return;
  int tap = i >> 12, rem = i & 4095;
  int cout = rem >> 6, cin = rem & 63;
  float x = w[cout * 576 + cin * 9 + tap];
  unsigned short h = f2bf(x);
  hi[i] = h; lo[i] = f2bf(x - bf2f(h));
}

// ---- conv3 implicit-GEMM MFMA bf16x3 (unchanged) ----
__global__ __launch_bounds__(256) void conv3_mfma(const unsigned short* __restrict__ xhi,
    const unsigned short* __restrict__ xlo, const unsigned short* __restrict__ whi,
    const unsigned short* __restrict__ wlo, const float* __restrict__ bias,
    unsigned short* __restrict__ bhi, unsigned short* __restrict__ blo)
{
  int wv = threadIdx.x >> 6, lane = threadIdx.x & 63;
  int b = blockIdx.y;
  int job = blockIdx.x * 4 + wv;      // 0..35
  int mpair = job >> 1, npair = job & 1;
  int l15 = lane & 15, kg = lane >> 4;
  int pos0 = mpair * 32 + l15;
  int pos1 = pos0 + 16;
  int y0 = pos0 / 24, x0 = pos0 % 24;
  int y1 = pos1 / 24, x1 = pos1 % 24;
  size_t boff = (size_t)b * 43264;    // 26*26*64
  int ia0 = (y0 * 26 + x0) * 64 + kg * 8;
  int ia1 = (y1 * 26 + x1) * 64 + kg * 8;
  int co0 = npair * 32 + l15;
  int co1 = co0 + 16;
  int ib0 = co0 * 64 + kg * 8;
  int ib1 = co1 * 64 + kg * 8;
  f32x4 a00 = {0,0,0,0}, a01 = {0,0,0,0}, a10 = {0,0,0,0}, a11 = {0,0,0,0};
#pragma unroll 3
  for (int tap = 0; tap < 9; ++tap) {
    int kh = tap / 3, kw = tap % 3;
    int toff = (kh * 26 + kw) * 64;
    int wboff = tap * 4096;
#pragma unroll
    for (int ks = 0; ks < 2; ++ks) {
      int ko = ks * 32;
      short8 A0h = *(const short8*)(xhi + boff + ia0 + toff + ko);
      short8 A0l = *(const short8*)(xlo + boff + ia0 + toff + ko);
      short8 A1h = *(const short8*)(xhi + boff + ia1 + toff + ko);
      short8 A1l = *(const short8*)(xlo + boff + ia1 + toff + ko);
      short8 B0h = *(const short8*)(whi + wboff + ib0 + ko);
      short8 B0l = *(const short8*)(wlo + wboff + ib0 + ko);
      short8 B1h = *(const short8*)(whi + wboff + ib1 + ko);
      short8 B1l = *(const short8*)(wlo + wboff + ib1 + ko);
      a00 = __builtin_amdgcn_mfma_f32_16x16x32_bf16(A0h, B0h, a00, 0, 0, 0);
      a01 = __builtin_amdgcn_mfma_f32_16x16x32_bf16(A0h, B1h, a01, 0, 0, 0);
      a10 = __builtin_amdgcn_mfma_f32_16x16x32_bf16(A1h, B0h, a10, 0, 0, 0);
      a11 = __builtin_amdgcn_mfma_f32_16x16x32_bf16(A1h, B1h, a11, 0, 0, 0);
      a00 = __builtin_amdgcn_mfma_f32_16x16x32_bf16(A0h, B0l, a00, 0, 0, 0);
      a01 = __builtin_amdgcn_mfma_f32_16x16x32_bf16(A0h, B1l, a01, 0, 0, 0);
      a10 = __builtin_amdgcn_mfma_f32_16x16x32_bf16(A1h, B0l, a10, 0, 0, 0);
      a11 = __builtin_amdgcn_mfma_f32_16x16x32_bf16(A1h, B1l, a11, 0, 0, 0);
      a00 = __builtin_amdgcn_mfma_f32_16x16x32_bf16(A0l, B0h, a00, 0, 0, 0);
      a01 = __builtin_amdgcn_mfma_f32_16x16x32_bf16(A0l, B1h, a01, 0, 0, 0);
      a10 = __builtin_amdgcn_mfma_f32_16x16x32_bf16(A1l, B0h, a10, 0, 0, 0);
      a11 = __builtin_amdgcn_mfma_f32_16x16x32_bf16(A1l, B1h, a11, 0, 0, 0);
    }
  }
  float bia0 = bias[co0], bia1 = bias[co1];
  size_t ob = (size_t)b * KP;
#pragma unroll
  for (int r = 0; r < 4; ++r) {
    int p0 = mpair * 32 + kg * 4 + r;
    int p1 = p0 + 16;
    float v; unsigned short h;
    v = a00[r] + bia0; v = v > 0.f ? v : 0.f; h = f2bf(v);
    bhi[ob + (size_t)co0 * 576 + p0] = h; blo[ob + (size_t)co0 * 576 + p0] = f2bf(v - bf2f(h));
    v = a01[r] + bia1; v = v > 0.f ? v : 0.f; h = f2bf(v);
    bhi[ob + (size_t)co1 * 576 + p0] = h; blo[ob + (size_t)co1 * 576 + p0] = f2bf(v - bf2f(h));
    v = a10[r] + bia0; v = v > 0.f ? v : 0.f; h = f2bf(v);
    bhi[ob + (size_t)co0 * 576 + p1] = h; blo[ob + (size_t)co0 * 576 + p1] = f2bf(v - bf2f(h));
    v = a11[r] + bia1; v = v > 0.f ? v : 0.f; h = f2bf(v);
    bhi[ob + (size_t)co1 * 576 + p1] = h; blo[ob + (size_t)co1 * 576 + p1] = f2bf(v - bf2f(h));
  }
}

// ---- fill history tail + zero pad of base planes: k in [36864, 36960) ----
__global__ __launch_bounds__(128) void fill_hist(const float* __restrict__ hist,
    unsigned short* __restrict__ bhi, unsigned short* __restrict__ blo)
{
  int b = blockIdx.x, t = threadIdx.x;
  int k = FEAT + t;
  if (k >= KP) return;
  float x = (k < K1) ? hist[b * HIST + t] : 0.f;
  unsigned short h = f2bf(x);
  size_t o = (size_t)b * KP + k;
  bhi[o] = h; blo[o] = f2bf(x - bf2f(h));
}

// ---- fc1 weights [128][36954] -> bf16 hi/lo planes [128][36960] (zero-padded) ----
__global__ __launch_bounds__(256) void convert_w1(const float* __restrict__ w,
    unsigned short* __restrict__ hi, unsigned short* __restrict__ lo)
{
  int o = blockIdx.y;
  int k = blockIdx.x * 256 + threadIdx.x;
  if (k >= KP) return;
  float x = (k < K1) ? w[(size_t)o * K1 + k] : 0.f;
  unsigned short h = f2bf(x);
  unsigned short l = f2bf(x - bf2f(h));
  size_t p = (size_t)o * KP + k;
  hi[p] = h; lo[p] = l;
}

// ---------------- fc2 weight transpose: [256][128] -> [128][256] ----------------
__global__ __launch_bounds__(256) void transpose_fc2(const float* __restrict__ w,
                                                     float* __restrict__ wT)
{
  int idx = blockIdx.x * 256 + threadIdx.x;
  if (idx < 128 * 256) {
    int i = idx >> 8, j = idx & 255;
    wT[idx] = w[j * 128 + i];
  }
}

// ---- fc1 MFMA bf16x3 split-K (unchanged) ----
__global__ __launch_bounds__(256) void fc1_mfma(const unsigned short* __restrict__ bhi,
    const unsigned short* __restrict__ blo, const unsigned short* __restrict__ whi,
    const unsigned short* __restrict__ wlo, float* __restrict__ part)
{
  int w = threadIdx.x >> 6, lane = threadIdx.x & 63;
  int job = blockIdx.x * 4 + w;        // 0..63
  int mt2 = job & 7, nt = job >> 3;
  int ks = blockIdx.y;                 // 0..32
  int k0 = ks * 35 * 32;
  int l15 = lane & 15, kg = lane >> 4;
  int s0 = mt2 * 32 + l15;
  int o  = nt * 16 + l15;
  const unsigned short* pa0h = bhi + (size_t)s0 * KP + k0 + kg * 8;
  const unsigned short* pa1h = pa0h + (size_t)16 * KP;
  const unsigned short* pa0l = blo + (size_t)s0 * KP + k0 + kg * 8;
  const unsigned short* pa1l = pa0l + (size_t)16 * KP;
  const unsigned short* pbh  = whi + (size_t)o * KP + k0 + kg * 8;
  const unsigned short* pbl  = wlo + (size_t)o * KP + k0 + kg * 8;
  f32x4 acc0 = {0.f, 0.f, 0.f, 0.f}, acc1 = {0.f, 0.f, 0.f, 0.f};
#pragma unroll 1
  for (int i = 0; i < 35; ++i) {
    short8 a0h = *(const short8*)pa0h;
    short8 a1h = *(const short8*)pa1h;
    short8 a0l = *(const short8*)pa0l;
    short8 a1l = *(const short8*)pa1l;
    short8 bh  = *(const short8*)pbh;
    short8 bl  = *(const short8*)pbl;
    acc0 = __builtin_amdgcn_mfma_f32_16x16x32_bf16(a0h, bh, acc0, 0, 0, 0);
    acc1 = __builtin_amdgcn_mfma_f32_16x16x32_bf16(a1h, bh, acc1, 0, 0, 0);
    acc0 = __builtin_amdgcn_mfma_f32_16x16x32_bf16(a0h, bl, acc0, 0, 0, 0);
    acc1 = __builtin_amdgcn_mfma_f32_16x16x32_bf16(a1h, bl, acc1, 0, 0, 0);
    acc0 = __builtin_amdgcn_mfma_f32_16x16x32_bf16(a0l, bh, acc0, 0, 0, 0);
    acc1 = __builtin_amdgcn_mfma_f32_16x16x32_bf16(a1l, bh, acc1, 0, 0, 0);
    pa0h += 32; pa1h += 32; pa0l += 32; pa1l += 32; pbh += 32; pbl += 32;
  }
  float* pp0 = part + (((size_t)ks * 64 + job) * 2) * 256;
  float* pp1 = pp0 + 256;
#pragma unroll
  for (int r = 0; r < 4; ++r) {
    pp0[r * 64 + lane] = acc0[r];
    pp1[r * 64 + lane] = acc1[r];
  }
}

// ---- fixed-order split-K reduce ----
__global__ __launch_bounds__(256) void fc1_reduce(const float* __restrict__ part,
                                                  float* __restrict__ h1)
{
  int i = blockIdx.x * 256 + threadIdx.x;
  if (i >= 32768) return;
  int s = i >> 7, o = i & 127;
  int mt2 = s >> 5, ti = (s >> 4) & 1, nt = o >> 4;
  int job = nt * 8 + mt2;
  int r = s & 15, c = o & 15;
  int off = (job * 2 + ti) * 256 + (r & 3) * 64 + ((r >> 2) << 4) + c;
  float sum = 0.f;
#pragma unroll 1
  for (int ks = 0; ks < 33; ++ks) sum += part[(size_t)ks * 32768 + off];
  h1[i] = sum;
}

// ---------------- SNN simulation (unchanged) ----------------
__global__ __launch_bounds__(256) void snn_ker(const float* __restrict__ h1,
    const float* __restrict__ b1, const float* __restrict__ w2T,
    const float* __restrict__ b2p, const float* __restrict__ w3,
    const float* __restrict__ b3p, float* __restrict__ out)
{
  int b = blockIdx.x, t = threadIdx.x;
  __shared__ float spk1l[128];
  __shared__ float part[4][9];
  float h1v = 0.f;
  if (t < 128) h1v = h1[b * 128 + t] + b1[t];
  float b2 = b2p[t];
  float w3r[9];
#pragma unroll
  for (int j = 0; j < 9; ++j) w3r[j] = w3[j * 256 + t];
  float mem1 = 0.f, syn1 = 0.f, mem2 = 0.f, syn2 = 0.f;
  float syn3[9], mem3[9], pot[9];
#pragma unroll
  for (int j = 0; j < 9; ++j) { syn3[j] = 0.f; mem3[j] = 0.f; pot[j] = 0.f; }

#pragma unroll 1
  for (int step = 0; step < 10; ++step) {
    if (t < 128) {
      syn1 = ALPHA * syn1 + h1v;
      mem1 = BETA * mem1 + syn1;
      float s = (mem1 > 1.0f) ? 1.f : 0.f;
      spk1l[t] = s;
      mem1 -= s;
    }
    __syncthreads();
    float h2 = b2;
    for (int i = 0; i < 128; ++i) {
      if (spk1l[i] != 0.f) h2 += w2T[i * 256 + t];
    }
    syn2 = ALPHA * syn2 + h2;
    mem2 = BETA * mem2 + syn2;
    float s2 = (mem2 > 1.0f) ? 1.f : 0.f;
    mem2 -= s2;

    float v[9];
#pragma unroll
    for (int j = 0; j < 9; ++j) v[j] = s2 * w3r[j];
#pragma unroll
    for (int j = 0; j < 9; ++j) {
      v[j] += __shfl_down(v[j], 32);
      v[j] += __shfl_down(v[j], 16);
      v[j] += __shfl_down(v[j], 8);
      v[j] += __shfl_down(v[j], 4);
      v[j] += __shfl_down(v[j], 2);
      v[j] += __shfl_down(v[j], 1);
    }
    if ((t & 63) == 0) {
#pragma unroll
      for (int j = 0; j < 9; ++j) part[t >> 6][j] = v[j];
    }
    __syncthreads();
    if (t == 0) {
#pragma unroll
      for (int j = 0; j < 9; ++j) {
        float h3 = part[0][j] + part[1][j] + part[2][j] + part[3][j] + b3p[j];
        syn3[j] = ALPHA * syn3[j] + h3;
        mem3[j] = BETA * mem3[j] + syn3[j];
        pot[j] += mem3[j];
      }
    }
  }
  if (t == 0) {
#pragma unroll
    for (int j = 0; j < 9; ++j) out[b * 9 + j] = pot[j] / 10.0f;
  }
}

// ---------------- host ----------------
extern "C" void kernel_launch(void* const* d_in, const int* in_sizes, int n_in,
                              void* d_out, int out_size, void* d_ws, size_t ws_size,
                              hipStream_t stream)
{
  const float* state = (const float*)d_in[0];
  const float* hist  = (const float*)d_in[1];
  const float* c1w   = (const float*)d_in[2];
  const float* c1b   = (const float*)d_in[3];
  const float* c2w   = (const float*)d_in[4];
  const float* c2b   = (const float*)d_in[5];
  const float* c3w   = (const float*)d_in[6];
  const float* c3b   = (const float*)d_in[7];
  const float* f1w   = (const float*)d_in[8];
  const float* f1b   = (const float*)d_in[9];
  const float* f2w   = (const float*)d_in[10];
  const float* f2b   = (const float*)d_in[11];
  const float* f3w   = (const float*)d_in[12];
  const float* f3b   = (const float*)d_in[13];
  float* out = (float*)d_out;
  float* ws  = (float*)d_ws;

  // workspace (float offsets), peak ~27.0M floats (108 MB):
  //   c1hi [0, 6,195,200) c1lo [6,195,200, 12,390,400)   (half-batch, reused per pass;
  //        region later reused as: base_hi [0, 4,730,880) base_lo [4,730,880, 9,461,760)
  //        w1_hi [9,461,760, 11,827,200))
  //   c2hi [12,390,400, 17,928,192) c2lo [17,928,192, 23,465,984)
  //   w2hi [23,465,984, 23,482,368) w2lo [23,482,368, 23,498,752)
  //   w1lo [23,498,752, 25,864,192)
  //   w3hi [25,864,192, 25,882,624) w3lo [25,882,624, 25,901,056)
  //   partb [25,901,056, 26,982,400) h1 [26,982,400, 27,015,168) wT2 [27,015,168, 27,047,936)
  unsigned short* c1hi    = (unsigned short*)(ws);
  unsigned short* c1lo    = (unsigned short*)(ws + 6195200);
  unsigned short* base_hi = (unsigned short*)(ws);
  unsigned short* base_lo = (unsigned short*)(ws + 4730880);
  unsigned short* w1_hi   = (unsigned short*)(ws + 9461760);
  unsigned short* c2hi    = (unsigned short*)(ws + 12390400);
  unsigned short* c2lo    = (unsigned short*)(ws + 17928192);
  unsigned short* w2_hi   = (unsigned short*)(ws + 23465984);
  unsigned short* w2_lo   = (unsigned short*)(ws + 23482368);
  unsigned short* w1_lo   = (unsigned short*)(ws + 23498752);
  unsigned short* w3_hi   = (unsigned short*)(ws + 25864192);
  unsigned short* w3_lo   = (unsigned short*)(ws + 25882624);
  float* partb    = ws + 25901056;
  float* h1buf    = ws + 26982400;
  float* wT2      = ws + 27015168;

  convert_w2<<<dim3(128), 256, 0, stream>>>(c2w, w2_hi, w2_lo);
  // pass 1: batches 0..127
  conv1_ker<<<dim3(12, 128), 256, 0, stream>>>(state, c1w, c1b, c1hi, c1lo, 0);
  conv2_mfma<<<dim3(11, 128), 256, 0, stream>>>(c1hi, c1lo, w2_hi, w2_lo, c2b,
                                                c2hi, c2lo, 0);
  // pass 2: batches 128..255 (reuse c1 buffers)
  conv1_ker<<<dim3(12, 128), 256, 0, stream>>>(state, c1w, c1b, c1hi, c1lo, 128);
  conv2_mfma<<<dim3(11, 128), 256, 0, stream>>>(c1hi, c1lo, w2_hi, w2_lo, c2b,
                                                c2hi, c2lo, 128);
  // c1 dead -> region reused for base planes + w1_hi
  convert_w1<<<dim3(145, 128), 256, 0, stream>>>(f1w, w1_hi, w1_lo);
  convert_w3<<<dim3(144), 256, 0, stream>>>(c3w, w3_hi, w3_lo);
  fill_hist<<<dim3(256), 128, 0, stream>>>(hist, base_hi, base_lo);
  conv3_mfma<<<dim3(9, 256), 256, 0, stream>>>(c2hi, c2lo, w3_hi, w3_lo, c3b,
                                               base_hi, base_lo);
  transpose_fc2<<<dim3(128), 256, 0, stream>>>(f2w, wT2);
  fc1_mfma<<<dim3(16, 33), 256, 0, stream>>>(base_hi, base_lo, w1_hi, w1_lo, partb);
  fc1_reduce<<<dim3(128), 256, 0, stream>>>(partb, h1buf);
  snn_ker<<<dim3(256), 256, 0, stream>>>(h1buf, f1b, wT2, f2b, f3w, f3b, out);
}

// Round 8
// 643.909 us; speedup vs baseline: 1.7070x; 1.1089x over previous
//
#include <hip/hip_runtime.h>
#include <cstddef>
#include <cstdint>

#define ALPHA 0.9f
#define BETA  0.8f

// ---------------- sizes ----------------
// conv1: 32x3x8x8 s4 -> [256,32,55,55]   (channels-last bf16 hi/lo, two half-batch passes)
// conv2: 64x32x4x4 s2 -> [256,64,26,26]  (MFMA implicit GEMM, channels-last bf16 hi/lo)
// conv3: 64x64x3x3 s1 -> [256,64,24,24]  (MFMA implicit GEMM -> base planes, pos-major)
// base k-index is PERMUTED: feat k = pos*64+cout (w1 planes permuted to match);
// history tail [36864,36954) identity. KP = 36960 (= 33*35*32)
#define FEAT   36864
#define HIST   90
#define K1     36954
#define KP     36960

typedef __attribute__((ext_vector_type(8))) short short8;
typedef __attribute__((ext_vector_type(4))) float f32x4;

__device__ __forceinline__ unsigned short f2bf(float x) {
  unsigned u = __float_as_uint(x);
  return (unsigned short)((u + 0x7FFFu + ((u >> 16) & 1u)) >> 16);
}
__device__ __forceinline__ float bf2f(unsigned short h) {
  return __uint_as_float(((unsigned)h) << 16);
}

// ------- conv1: fp32 VALU, epilogue writes channels-last bf16 hi/lo [lb][pos][32] -------
__global__ __launch_bounds__(256) void conv1_ker(const float* __restrict__ in,
    const float* __restrict__ w, const float* __restrict__ bias,
    unsigned short* __restrict__ ohi, unsigned short* __restrict__ olo, int batch0)
{
  __shared__ float wl[192 * 32];   // [k][cout]
  int t = threadIdx.x;
  for (int idx = t; idx < 6144; idx += 256) {
    int co = idx / 192, k = idx % 192;
    wl[k * 32 + co] = w[idx];
  }
  __syncthreads();
  int b = blockIdx.y;              // local batch 0..127
  int pos = blockIdx.x * 256 + t;
  if (pos >= 55 * 55) return;
  int y = pos / 55, x = pos % 55;
  const float* ip = in + (size_t)(batch0 + b) * 3 * 224 * 224;
  float acc[32];
#pragma unroll
  for (int q = 0; q < 32; ++q) acc[q] = 0.f;
  for (int c = 0; c < 3; ++c) {
#pragma unroll
    for (int kh = 0; kh < 8; ++kh) {
      const float* r = ip + (size_t)(c * 224 + (y * 4 + kh)) * 224 + x * 4;
      const float4 i0 = *(const float4*)(r);
      const float4 i1 = *(const float4*)(r + 4);
      float iv[8] = {i0.x, i0.y, i0.z, i0.w, i1.x, i1.y, i1.z, i1.w};
#pragma unroll
      for (int kw = 0; kw < 8; ++kw) {
        const float4* wp = (const float4*)(wl + ((c * 8 + kh) * 8 + kw) * 32);
#pragma unroll
        for (int q = 0; q < 8; ++q) {
          float4 wv = wp[q];
          acc[q * 4 + 0] += iv[kw] * wv.x;
          acc[q * 4 + 1] += iv[kw] * wv.y;
          acc[q * 4 + 2] += iv[kw] * wv.z;
          acc[q * 4 + 3] += iv[kw] * wv.w;
        }
      }
    }
  }
  size_t ob = ((size_t)b * 3025 + pos) * 32;
#pragma unroll
  for (int g = 0; g < 4; ++g) {
    short8 hv, lv;
#pragma unroll
    for (int q = 0; q < 8; ++q) {
      float v = acc[g * 8 + q] + bias[g * 8 + q];
      v = v > 0.f ? v : 0.f;
      unsigned short hh = f2bf(v);
      hv[q] = (short)hh; lv[q] = (short)f2bf(v - bf2f(hh));
    }
    *(short8*)(ohi + ob + g * 8) = hv;
    *(short8*)(olo + ob + g * 8) = lv;
  }
}

// ---- conv2 weights [64][32][4][4] fp32 -> [tap][cout][cin] bf16 hi/lo ----
__global__ __launch_bounds__(256) void convert_w2(const float* __restrict__ w,
    unsigned short* __restrict__ hi, unsigned short* __restrict__ lo)
{
  int i = blockIdx.x * 256 + threadIdx.x;
  if (i >= 16 * 64 * 32) return;
  int tap = i >> 11, rem = i & 2047;
  int co = rem >> 5, ci = rem & 31;
  float x = w[co * 512 + ci * 16 + tap];
  unsigned short h = f2bf(x);
  hi[i] = h; lo[i] = f2bf(x - bf2f(h));
}

// ---- conv2 implicit-GEMM MFMA bf16x3 (unchanged) ----
__global__ __launch_bounds__(256) void conv2_mfma(const unsigned short* __restrict__ xhi,
    const unsigned short* __restrict__ xlo, const unsigned short* __restrict__ whi,
    const unsigned short* __restrict__ wlo, const float* __restrict__ bias,
    unsigned short* __restrict__ ohi, unsigned short* __restrict__ olo, int batch0)
{
  int wv = threadIdx.x >> 6, lane = threadIdx.x & 63;
  int b = blockIdx.y;                 // local batch 0..127
  int job = blockIdx.x * 4 + wv;      // 0..43
  int mpair = job >> 1, npair = job & 1;
  int l15 = lane & 15, kg = lane >> 4;
  int pos0 = mpair * 32 + l15;
  int pos1 = pos0 + 16;
  int cp0 = pos0 > 675 ? 675 : pos0;
  int cp1 = pos1 > 675 ? 675 : pos1;
  int y0 = cp0 / 26, x0 = cp0 % 26;
  int y1 = cp1 / 26, x1 = cp1 % 26;
  size_t ibase = (size_t)b * 96800;   // 3025*32
  int co0 = npair * 32 + l15;
  int co1 = co0 + 16;
  int ib0 = co0 * 32 + kg * 8;
  int ib1 = co1 * 32 + kg * 8;
  f32x4 a00 = {0,0,0,0}, a01 = {0,0,0,0}, a10 = {0,0,0,0}, a11 = {0,0,0,0};
#pragma unroll 4
  for (int tap = 0; tap < 16; ++tap) {
    int kh = tap >> 2, kw = tap & 3;
    int ia0 = ((2 * y0 + kh) * 55 + 2 * x0 + kw) * 32 + kg * 8;
    int ia1 = ((2 * y1 + kh) * 55 + 2 * x1 + kw) * 32 + kg * 8;
    int wb = tap * 2048;
    short8 A0h = *(const short8*)(xhi + ibase + ia0);
    short8 A0l = *(const short8*)(xlo + ibase + ia0);
    short8 A1h = *(const short8*)(xhi + ibase + ia1);
    short8 A1l = *(const short8*)(xlo + ibase + ia1);
    short8 B0h = *(const short8*)(whi + wb + ib0);
    short8 B0l = *(const short8*)(wlo + wb + ib0);
    short8 B1h = *(const short8*)(whi + wb + ib1);
    short8 B1l = *(const short8*)(wlo + wb + ib1);
    a00 = __builtin_amdgcn_mfma_f32_16x16x32_bf16(A0h, B0h, a00, 0, 0, 0);
    a01 = __builtin_amdgcn_mfma_f32_16x16x32_bf16(A0h, B1h, a01, 0, 0, 0);
    a10 = __builtin_amdgcn_mfma_f32_16x16x32_bf16(A1h, B0h, a10, 0, 0, 0);
    a11 = __builtin_amdgcn_mfma_f32_16x16x32_bf16(A1h, B1h, a11, 0, 0, 0);
    a00 = __builtin_amdgcn_mfma_f32_16x16x32_bf16(A0h, B0l, a00, 0, 0, 0);
    a01 = __builtin_amdgcn_mfma_f32_16x16x32_bf16(A0h, B1l, a01, 0, 0, 0);
    a10 = __builtin_amdgcn_mfma_f32_16x16x32_bf16(A1h, B0l, a10, 0, 0, 0);
    a11 = __builtin_amdgcn_mfma_f32_16x16x32_bf16(A1h, B1l, a11, 0, 0, 0);
    a00 = __builtin_amdgcn_mfma_f32_16x16x32_bf16(A0l, B0h, a00, 0, 0, 0);
    a01 = __builtin_amdgcn_mfma_f32_16x16x32_bf16(A0l, B1h, a01, 0, 0, 0);
    a10 = __builtin_amdgcn_mfma_f32_16x16x32_bf16(A1l, B0h, a10, 0, 0, 0);
    a11 = __builtin_amdgcn_mfma_f32_16x16x32_bf16(A1l, B1h, a11, 0, 0, 0);
  }
  float bia0 = bias[co0], bia1 = bias[co1];
  size_t obase = (size_t)(batch0 + b) * 676;
#pragma unroll
  for (int r = 0; r < 4; ++r) {
    int p0 = mpair * 32 + kg * 4 + r;
    int p1 = p0 + 16;
    float v; unsigned short h;
    if (p0 < 676) {
      size_t o = (obase + p0) * 64;
      v = a00[r] + bia0; v = v > 0.f ? v : 0.f; h = f2bf(v);
      ohi[o + co0] = h; olo[o + co0] = f2bf(v - bf2f(h));
      v = a01[r] + bia1; v = v > 0.f ? v : 0.f; h = f2bf(v);
      ohi[o + co1] = h; olo[o + co1] = f2bf(v - bf2f(h));
    }
    if (p1 < 676) {
      size_t o = (obase + p1) * 64;
      v = a10[r] + bia0; v = v > 0.f ? v : 0.f; h = f2bf(v);
      ohi[o + co0] = h; olo[o + co0] = f2bf(v - bf2f(h));
      v = a11[r] + bia1; v = v > 0.f ? v : 0.f; h = f2bf(v);
      ohi[o + co1] = h; olo[o + co1] = f2bf(v - bf2f(h));
    }
  }
}

// ---- conv3 weights [cout][cin][3][3] fp32 -> [tap][cout][cin] bf16 hi/lo ----
__global__ __launch_bounds__(256) void convert_w3(const float* __restrict__ w,
    unsigned short* __restrict__ hi, unsigned short* __restrict__ lo)
{
  int i = blockIdx.x * 256 + threadIdx.x;
  if (i >= 9 * 64 * 64) return;
  int tap = i >> 12, rem = i & 4095;
  int cout = rem >> 6, cin = rem & 63;
  float x = w[cout * 576 + cin * 9 + tap];
  unsigned short h = f2bf(x);
  hi[i] = h; lo[i] = f2bf(x - bf2f(h));
}

// ---- conv3 implicit-GEMM MFMA bf16x3 v2: wave = 48 pos x 64 cout ----
// grid (3, 256): block covers 192 pos; wave wv covers pos [bx*192+wv*48, +48).
// epilogue writes base planes POS-MAJOR: base[b][pos*64+cout] (coalesced).
__global__ __launch_bounds__(256) void conv3_mfma(const unsigned short* __restrict__ xhi,
    const unsigned short* __restrict__ xlo, const unsigned short* __restrict__ whi,
    const unsigned short* __restrict__ wlo, const float* __restrict__ bias,
    unsigned short* __restrict__ bhi, unsigned short* __restrict__ blo)
{
  int wv = threadIdx.x >> 6, lane = threadIdx.x & 63;
  int b = blockIdx.y;
  int l15 = lane & 15, kg = lane >> 4;
  int posbase = blockIdx.x * 192 + wv * 48;
  int rowcol[3];
#pragma unroll
  for (int i = 0; i < 3; ++i) {
    int pos = posbase + i * 16 + l15;
    int y = pos / 24, x = pos % 24;
    rowcol[i] = (y * 26 + x) * 64;
  }
  const unsigned short* xh = xhi + (size_t)b * 43264;
  const unsigned short* xl = xlo + (size_t)b * 43264;
  int ibn[4];
#pragma unroll
  for (int nt = 0; nt < 4; ++nt) ibn[nt] = (nt * 16 + l15) * 64;
  f32x4 acc[3][4];
#pragma unroll
  for (int i = 0; i < 3; ++i)
#pragma unroll
    for (int nt = 0; nt < 4; ++nt) acc[i][nt] = (f32x4){0.f, 0.f, 0.f, 0.f};

#pragma unroll 1
  for (int tap = 0; tap < 9; ++tap) {
    int kh = tap / 3, kw = tap % 3;
    int toff = (kh * 26 + kw) * 64 + kg * 8;
    int wboff = tap * 4096 + kg * 8;
#pragma unroll
    for (int ks = 0; ks < 2; ++ks) {
      int ko = ks * 32;
      short8 Ah[3], Al[3], Bh[4], Bl[4];
#pragma unroll
      for (int i = 0; i < 3; ++i) {
        Ah[i] = *(const short8*)(xh + rowcol[i] + toff + ko);
        Al[i] = *(const short8*)(xl + rowcol[i] + toff + ko);
      }
#pragma unroll
      for (int nt = 0; nt < 4; ++nt) {
        Bh[nt] = *(const short8*)(whi + wboff + ibn[nt] + ko);
        Bl[nt] = *(const short8*)(wlo + wboff + ibn[nt] + ko);
      }
#pragma unroll
      for (int i = 0; i < 3; ++i)
#pragma unroll
        for (int nt = 0; nt < 4; ++nt) {
          acc[i][nt] = __builtin_amdgcn_mfma_f32_16x16x32_bf16(Ah[i], Bh[nt], acc[i][nt], 0, 0, 0);
          acc[i][nt] = __builtin_amdgcn_mfma_f32_16x16x32_bf16(Ah[i], Bl[nt], acc[i][nt], 0, 0, 0);
          acc[i][nt] = __builtin_amdgcn_mfma_f32_16x16x32_bf16(Al[i], Bh[nt], acc[i][nt], 0, 0, 0);
        }
    }
  }
  // epilogue: D row = kg*4+r -> pos, col = l15 -> cout (within nt tile). Pos-major writes.
  float bv[4];
#pragma unroll
  for (int nt = 0; nt < 4; ++nt) bv[nt] = bias[nt * 16 + l15];
  size_t ob = (size_t)b * KP;
#pragma unroll
  for (int i = 0; i < 3; ++i) {
#pragma unroll
    for (int r = 0; r < 4; ++r) {
      int pos = posbase + i * 16 + kg * 4 + r;
      size_t o = ob + (size_t)pos * 64 + l15;
#pragma unroll
      for (int nt = 0; nt < 4; ++nt) {
        float v = acc[i][nt][r] + bv[nt];
        v = v > 0.f ? v : 0.f;
        unsigned short h = f2bf(v);
        bhi[o + nt * 16] = h;
        blo[o + nt * 16] = f2bf(v - bf2f(h));
      }
    }
  }
}

// ---- fill history tail + zero pad of base planes: k in [36864, 36960), identity ----
__global__ __launch_bounds__(128) void fill_hist(const float* __restrict__ hist,
    unsigned short* __restrict__ bhi, unsigned short* __restrict__ blo)
{
  int b = blockIdx.x, t = threadIdx.x;
  int k = FEAT + t;
  if (k >= KP) return;
  float x = (k < K1) ? hist[b * HIST + t] : 0.f;
  unsigned short h = f2bf(x);
  size_t o = (size_t)b * KP + k;
  bhi[o] = h; blo[o] = f2bf(x - bf2f(h));
}

// ---- fc1 weights feat part, PERMUTED to pos-major: dst[o][pos*64+c] = w[o][c*576+pos] ----
// tiled LDS transpose; grid (9, 128): blockIdx.x = 64-pos tile, blockIdx.y = o
__global__ __launch_bounds__(256) void convert_w1(const float* __restrict__ w,
    unsigned short* __restrict__ hi, unsigned short* __restrict__ lo)
{
  __shared__ float tl[64][65];
  int o = blockIdx.y;
  int p0 = blockIdx.x * 64;
  int t = threadIdx.x;
  const float* src = w + (size_t)o * K1;
  for (int e = t; e < 4096; e += 256) {
    int c = e >> 6, p = e & 63;
    tl[p][c] = src[c * 576 + p0 + p];
  }
  __syncthreads();
  size_t dbase = (size_t)o * KP;
  for (int e = t; e < 4096; e += 256) {
    int p = e >> 6, c = e & 63;
    float x = tl[p][c];
    unsigned short h = f2bf(x);
    size_t d = dbase + (size_t)(p0 + p) * 64 + c;
    hi[d] = h; lo[d] = f2bf(x - bf2f(h));
  }
}

// ---- fc1 weights history tail [36864, 36960), identity mapping ----
__global__ __launch_bounds__(128) void convert_w1_tail(const float* __restrict__ w,
    unsigned short* __restrict__ hi, unsigned short* __restrict__ lo)
{
  int o = blockIdx.x, t = threadIdx.x;
  int k = FEAT + t;
  if (k >= KP) return;
  float x = (k < K1) ? w[(size_t)o * K1 + k] : 0.f;
  unsigned short h = f2bf(x);
  size_t p = (size_t)o * KP + k;
  hi[p] = h; lo[p] = f2bf(x - bf2f(h));
}

// ---------------- fc2 weight transpose: [256][128] -> [128][256] ----------------
__global__ __launch_bounds__(256) void transpose_fc2(const float* __restrict__ w,
                                                     float* __restrict__ wT)
{
  int idx = blockIdx.x * 256 + threadIdx.x;
  if (idx < 128 * 256) {
    int i = idx >> 8, j = idx & 255;
    wT[idx] = w[j * 128 + i];
  }
}

// ---- fc1 MFMA bf16x3 split-K (unchanged; operates on permuted planes) ----
__global__ __launch_bounds__(256) void fc1_mfma(const unsigned short* __restrict__ bhi,
    const unsigned short* __restrict__ blo, const unsigned short* __restrict__ whi,
    const unsigned short* __restrict__ wlo, float* __restrict__ part)
{
  int w = threadIdx.x >> 6, lane = threadIdx.x & 63;
  int job = blockIdx.x * 4 + w;        // 0..63
  int mt2 = job & 7, nt = job >> 3;
  int ks = blockIdx.y;                 // 0..32
  int k0 = ks * 35 * 32;
  int l15 = lane & 15, kg = lane >> 4;
  int s0 = mt2 * 32 + l15;
  int o  = nt * 16 + l15;
  const unsigned short* pa0h = bhi + (size_t)s0 * KP + k0 + kg * 8;
  const unsigned short* pa1h = pa0h + (size_t)16 * KP;
  const unsigned short* pa0l = blo + (size_t)s0 * KP + k0 + kg * 8;
  const unsigned short* pa1l = pa0l + (size_t)16 * KP;
  const unsigned short* pbh  = whi + (size_t)o * KP + k0 + kg * 8;
  const unsigned short* pbl  = wlo + (size_t)o * KP + k0 + kg * 8;
  f32x4 acc0 = {0.f, 0.f, 0.f, 0.f}, acc1 = {0.f, 0.f, 0.f, 0.f};
#pragma unroll 1
  for (int i = 0; i < 35; ++i) {
    short8 a0h = *(const short8*)pa0h;
    short8 a1h = *(const short8*)pa1h;
    short8 a0l = *(const short8*)pa0l;
    short8 a1l = *(const short8*)pa1l;
    short8 bh  = *(const short8*)pbh;
    short8 bl  = *(const short8*)pbl;
    acc0 = __builtin_amdgcn_mfma_f32_16x16x32_bf16(a0h, bh, acc0, 0, 0, 0);
    acc1 = __builtin_amdgcn_mfma_f32_16x16x32_bf16(a1h, bh, acc1, 0, 0, 0);
    acc0 = __builtin_amdgcn_mfma_f32_16x16x32_bf16(a0h, bl, acc0, 0, 0, 0);
    acc1 = __builtin_amdgcn_mfma_f32_16x16x32_bf16(a1h, bl, acc1, 0, 0, 0);
    acc0 = __builtin_amdgcn_mfma_f32_16x16x32_bf16(a0l, bh, acc0, 0, 0, 0);
    acc1 = __builtin_amdgcn_mfma_f32_16x16x32_bf16(a1l, bh, acc1, 0, 0, 0);
    pa0h += 32; pa1h += 32; pa0l += 32; pa1l += 32; pbh += 32; pbl += 32;
  }
  float* pp0 = part + (((size_t)ks * 64 + job) * 2) * 256;
  float* pp1 = pp0 + 256;
#pragma unroll
  for (int r = 0; r < 4; ++r) {
    pp0[r * 64 + lane] = acc0[r];
    pp1[r * 64 + lane] = acc1[r];
  }
}

// ---- fixed-order split-K reduce ----
__global__ __launch_bounds__(256) void fc1_reduce(const float* __restrict__ part,
                                                  float* __restrict__ h1)
{
  int i = blockIdx.x * 256 + threadIdx.x;
  if (i >= 32768) return;
  int s = i >> 7, o = i & 127;
  int mt2 = s >> 5, ti = (s >> 4) & 1, nt = o >> 4;
  int job = nt * 8 + mt2;
  int r = s & 15, c = o & 15;
  int off = (job * 2 + ti) * 256 + (r & 3) * 64 + ((r >> 2) << 4) + c;
  float sum = 0.f;
#pragma unroll 1
  for (int ks = 0; ks < 33; ++ks) sum += part[(size_t)ks * 32768 + off];
  h1[i] = sum;
}

// ---------------- SNN simulation (unchanged) ----------------
__global__ __launch_bounds__(256) void snn_ker(const float* __restrict__ h1,
    const float* __restrict__ b1, const float* __restrict__ w2T,
    const float* __restrict__ b2p, const float* __restrict__ w3,
    const float* __restrict__ b3p, float* __restrict__ out)
{
  int b = blockIdx.x, t = threadIdx.x;
  __shared__ float spk1l[128];
  __shared__ float part[4][9];
  float h1v = 0.f;
  if (t < 128) h1v = h1[b * 128 + t] + b1[t];
  float b2 = b2p[t];
  float w3r[9];
#pragma unroll
  for (int j = 0; j < 9; ++j) w3r[j] = w3[j * 256 + t];
  float mem1 = 0.f, syn1 = 0.f, mem2 = 0.f, syn2 = 0.f;
  float syn3[9], mem3[9], pot[9];
#pragma unroll
  for (int j = 0; j < 9; ++j) { syn3[j] = 0.f; mem3[j] = 0.f; pot[j] = 0.f; }

#pragma unroll 1
  for (int step = 0; step < 10; ++step) {
    if (t < 128) {
      syn1 = ALPHA * syn1 + h1v;
      mem1 = BETA * mem1 + syn1;
      float s = (mem1 > 1.0f) ? 1.f : 0.f;
      spk1l[t] = s;
      mem1 -= s;
    }
    __syncthreads();
    float h2 = b2;
    for (int i = 0; i < 128; ++i) {
      if (spk1l[i] != 0.f) h2 += w2T[i * 256 + t];
    }
    syn2 = ALPHA * syn2 + h2;
    mem2 = BETA * mem2 + syn2;
    float s2 = (mem2 > 1.0f) ? 1.f : 0.f;
    mem2 -= s2;

    float v[9];
#pragma unroll
    for (int j = 0; j < 9; ++j) v[j] = s2 * w3r[j];
#pragma unroll
    for (int j = 0; j < 9; ++j) {
      v[j] += __shfl_down(v[j], 32);
      v[j] += __shfl_down(v[j], 16);
      v[j] += __shfl_down(v[j], 8);
      v[j] += __shfl_down(v[j], 4);
      v[j] += __shfl_down(v[j], 2);
      v[j] += __shfl_down(v[j], 1);
    }
    if ((t & 63) == 0) {
#pragma unroll
      for (int j = 0; j < 9; ++j) part[t >> 6][j] = v[j];
    }
    __syncthreads();
    if (t == 0) {
#pragma unroll
      for (int j = 0; j < 9; ++j) {
        float h3 = part[0][j] + part[1][j] + part[2][j] + part[3][j] + b3p[j];
        syn3[j] = ALPHA * syn3[j] + h3;
        mem3[j] = BETA * mem3[j] + syn3[j];
        pot[j] += mem3[j];
      }
    }
  }
  if (t == 0) {
#pragma unroll
    for (int j = 0; j < 9; ++j) out[b * 9 + j] = pot[j] / 10.0f;
  }
}

// ---------------- host ----------------
extern "C" void kernel_launch(void* const* d_in, const int* in_sizes, int n_in,
                              void* d_out, int out_size, void* d_ws, size_t ws_size,
                              hipStream_t stream)
{
  const float* state = (const float*)d_in[0];
  const float* hist  = (const float*)d_in[1];
  const float* c1w   = (const float*)d_in[2];
  const float* c1b   = (const float*)d_in[3];
  const float* c2w   = (const float*)d_in[4];
  const float* c2b   = (const float*)d_in[5];
  const float* c3w   = (const float*)d_in[6];
  const float* c3b   = (const float*)d_in[7];
  const float* f1w   = (const float*)d_in[8];
  const float* f1b   = (const float*)d_in[9];
  const float* f2w   = (const float*)d_in[10];
  const float* f2b   = (const float*)d_in[11];
  const float* f3w   = (const float*)d_in[12];
  const float* f3b   = (const float*)d_in[13];
  float* out = (float*)d_out;
  float* ws  = (float*)d_ws;

  // workspace (float offsets), peak ~27.0M floats (108 MB):
  //   c1hi [0, 6,195,200) c1lo [6,195,200, 12,390,400)   (half-batch, reused per pass;
  //        region later reused as: base_hi [0, 4,730,880) base_lo [4,730,880, 9,461,760)
  //        w1_hi [9,461,760, 11,827,200))
  //   c2hi [12,390,400, 17,928,192) c2lo [17,928,192, 23,465,984)
  //   w2hi [23,465,984, 23,482,368) w2lo [23,482,368, 23,498,752)
  //   w1lo [23,498,752, 25,864,192)
  //   w3hi [25,864,192, 25,882,624) w3lo [25,882,624, 25,901,056)
  //   partb [25,901,056, 26,982,400) h1 [26,982,400, 27,015,168) wT2 [27,015,168, 27,047,936)
  unsigned short* c1hi    = (unsigned short*)(ws);
  unsigned short* c1lo    = (unsigned short*)(ws + 6195200);
  unsigned short* base_hi = (unsigned short*)(ws);
  unsigned short* base_lo = (unsigned short*)(ws + 4730880);
  unsigned short* w1_hi   = (unsigned short*)(ws + 9461760);
  unsigned short* c2hi    = (unsigned short*)(ws + 12390400);
  unsigned short* c2lo    = (unsigned short*)(ws + 17928192);
  unsigned short* w2_hi   = (unsigned short*)(ws + 23465984);
  unsigned short* w2_lo   = (unsigned short*)(ws + 23482368);
  unsigned short* w1_lo   = (unsigned short*)(ws + 23498752);
  unsigned short* w3_hi   = (unsigned short*)(ws + 25864192);
  unsigned short* w3_lo   = (unsigned short*)(ws + 25882624);
  float* partb    = ws + 25901056;
  float* h1buf    = ws + 26982400;
  float* wT2      = ws + 27015168;

  convert_w2<<<dim3(128), 256, 0, stream>>>(c2w, w2_hi, w2_lo);
  // pass 1: batches 0..127
  conv1_ker<<<dim3(12, 128), 256, 0, stream>>>(state, c1w, c1b, c1hi, c1lo, 0);
  conv2_mfma<<<dim3(11, 128), 256, 0, stream>>>(c1hi, c1lo, w2_hi, w2_lo, c2b,
                                                c2hi, c2lo, 0);
  // pass 2: batches 128..255 (reuse c1 buffers)
  conv1_ker<<<dim3(12, 128), 256, 0, stream>>>(state, c1w, c1b, c1hi, c1lo, 128);
  conv2_mfma<<<dim3(11, 128), 256, 0, stream>>>(c1hi, c1lo, w2_hi, w2_lo, c2b,
                                                c2hi, c2lo, 128);
  // c1 dead -> region reused for base planes + w1_hi
  convert_w1<<<dim3(9, 128), 256, 0, stream>>>(f1w, w1_hi, w1_lo);
  convert_w1_tail<<<dim3(128), 128, 0, stream>>>(f1w, w1_hi, w1_lo);
  convert_w3<<<dim3(144), 256, 0, stream>>>(c3w, w3_hi, w3_lo);
  fill_hist<<<dim3(256), 128, 0, stream>>>(hist, base_hi, base_lo);
  conv3_mfma<<<dim3(3, 256), 256, 0, stream>>>(c2hi, c2lo, w3_hi, w3_lo, c3b,
                                               base_hi, base_lo);
  transpose_fc2<<<dim3(128), 256, 0, stream>>>(f2w, wT2);
  fc1_mfma<<<dim3(16, 33), 256, 0, stream>>>(base_hi, base_lo, w1_hi, w1_lo, partb);
  fc1_reduce<<<dim3(128), 256, 0, stream>>>(partb, h1buf);
  snn_ker<<<dim3(256), 256, 0, stream>>>(h1buf, f1b, wT2, f2b, f3w, f3b, out);
}

// Round 10
// 560.661 us; speedup vs baseline: 1.9604x; 1.1485x over previous
//
#include <hip/hip_runtime.h>
#include <cstddef>
#include <cstdint>

#define ALPHA 0.9f
#define BETA  0.8f

// ---------------- sizes ----------------
// conv1: 32x3x8x8 s4 -> [256,32,55,55]   (MFMA implicit GEMM bf16x4, quarter-batch)
// conv2: 64x32x4x4 s2 -> [256,64,26,26]  (MFMA implicit GEMM bf16x3, channels-last)
// conv3: 64x64x3x3 s1 -> [256,64,24,24]  (MFMA implicit GEMM bf16x3 -> base planes, pos-major)
// base k-index is PERMUTED: feat k = pos*64+cout (w1 planes permuted to match);
// history tail [36864,36954) identity. KP = 36960 (= 33*35*32)
#define FEAT   36864
#define HIST   90
#define K1     36954
#define KP     36960

typedef __attribute__((ext_vector_type(8))) short short8;
typedef __attribute__((ext_vector_type(4))) float f32x4;
typedef __attribute__((ext_vector_type(2))) int int2v;

__device__ __forceinline__ unsigned short f2bf(float x) {
  unsigned u = __float_as_uint(x);
  return (unsigned short)((u + 0x7FFFu + ((u >> 16) & 1u)) >> 16);
}
__device__ __forceinline__ float bf2f(unsigned short h) {
  return __uint_as_float(((unsigned)h) << 16);
}
// 8-short load from an 8-byte-aligned (not necessarily 16B) address
__device__ __forceinline__ short8 ld8u(const unsigned short* p) {
  int2v a = *(const int2v*)(p);
  int2v b = *(const int2v*)(p + 4);
  union { int2v i[2]; short8 s; } u;
  u.i[0] = a; u.i[1] = b;
  return u.s;
}

// ---- state fp32 -> bf16 hi/lo planes (quarter batch: 64*3*224*224 = 9,633,792 elems) ----
__global__ __launch_bounds__(256) void convert_state(const float* __restrict__ in,
    unsigned short* __restrict__ hi, unsigned short* __restrict__ lo)
{
  size_t idx = ((size_t)blockIdx.x * 256 + threadIdx.x) * 8;
  if (idx >= 9633792) return;
  const float4 f0 = *(const float4*)(in + idx);
  const float4 f1 = *(const float4*)(in + idx + 4);
  float v[8] = {f0.x, f0.y, f0.z, f0.w, f1.x, f1.y, f1.z, f1.w};
  short8 h8, l8;
#pragma unroll
  for (int q = 0; q < 8; ++q) {
    unsigned short h = f2bf(v[q]);
    h8[q] = (short)h; l8[q] = (short)f2bf(v[q] - bf2f(h));
  }
  *(short8*)(hi + idx) = h8;
  *(short8*)(lo + idx) = l8;
}

// ---- conv1 weights [32][3][8][8] -> [pair=c*8+kh][cout][kw] bf16 hi/lo ----
__global__ __launch_bounds__(256) void convert_w1c(const float* __restrict__ w,
    unsigned short* __restrict__ hi, unsigned short* __restrict__ lo)
{
  int i = blockIdx.x * 256 + threadIdx.x;
  if (i >= 6144) return;
  int kw = i & 7, rest = i >> 3;
  int cout = rest & 31, pair = rest >> 5;
  int c = pair >> 3, kh = pair & 7;
  float x = w[((cout * 3 + c) * 8 + kh) * 8 + kw];
  unsigned short h = f2bf(x);
  hi[i] = h; lo[i] = f2bf(x - bf2f(h));
}

// ---- conv1 implicit-GEMM MFMA bf16x4 (all 4 products): wave = 48 pos x 32 cout ----
// k-order: pair = c*8+kh (k-group), kw = j. A lane loads 8 contiguous input pixels.
// grid (16, 64): block = 192 pos; output channels-last [lb][pos][32] bf16 hi/lo.
__global__ __launch_bounds__(256) void conv1_mfma(const unsigned short* __restrict__ xhi,
    const unsigned short* __restrict__ xlo, const unsigned short* __restrict__ whi,
    const unsigned short* __restrict__ wlo, const float* __restrict__ bias,
    unsigned short* __restrict__ ohi, unsigned short* __restrict__ olo)
{
  int wv = threadIdx.x >> 6, lane = threadIdx.x & 63;
  int b = blockIdx.y;             // local batch 0..63
  int l15 = lane & 15, kg = lane >> 4;
  int posbase = blockIdx.x * 192 + wv * 48;
  int rowb[3];
#pragma unroll
  for (int i = 0; i < 3; ++i) {
    int pos = posbase + i * 16 + l15;
    int cp = pos > 3024 ? 3024 : pos;
    int y = cp / 55, x = cp % 55;
    rowb[i] = (y * 4) * 224 + x * 4;
  }
  const unsigned short* xh = xhi + (size_t)b * 150528;
  const unsigned short* xl = xlo + (size_t)b * 150528;
  f32x4 acc[3][2];
#pragma unroll
  for (int i = 0; i < 3; ++i) {
    acc[i][0] = (f32x4){0.f, 0.f, 0.f, 0.f};
    acc[i][1] = (f32x4){0.f, 0.f, 0.f, 0.f};
  }
#pragma unroll 2
  for (int s = 0; s < 6; ++s) {
    int pair = s * 4 + kg;
    int c = pair >> 3, kh = pair & 7;
    int aoff = c * 50176 + kh * 224;
    short8 Ah[3], Al[3], Bh[2], Bl[2];
#pragma unroll
    for (int i = 0; i < 3; ++i) {
      Ah[i] = ld8u(xh + aoff + rowb[i]);
      Al[i] = ld8u(xl + aoff + rowb[i]);
    }
    int wb = (pair * 32 + l15) * 8;
#pragma unroll
    for (int nt = 0; nt < 2; ++nt) {
      Bh[nt] = *(const short8*)(whi + wb + nt * 128);
      Bl[nt] = *(const short8*)(wlo + wb + nt * 128);
    }
#pragma unroll
    for (int i = 0; i < 3; ++i)
#pragma unroll
      for (int nt = 0; nt < 2; ++nt) {
        acc[i][nt] = __builtin_amdgcn_mfma_f32_16x16x32_bf16(Ah[i], Bh[nt], acc[i][nt], 0, 0, 0);
        acc[i][nt] = __builtin_amdgcn_mfma_f32_16x16x32_bf16(Ah[i], Bl[nt], acc[i][nt], 0, 0, 0);
        acc[i][nt] = __builtin_amdgcn_mfma_f32_16x16x32_bf16(Al[i], Bh[nt], acc[i][nt], 0, 0, 0);
        acc[i][nt] = __builtin_amdgcn_mfma_f32_16x16x32_bf16(Al[i], Bl[nt], acc[i][nt], 0, 0, 0);
      }
  }
  float bv0 = bias[l15], bv1 = bias[16 + l15];
#pragma unroll
  for (int i = 0; i < 3; ++i) {
#pragma unroll
    for (int r = 0; r < 4; ++r) {
      int pos = posbase + i * 16 + kg * 4 + r;
      if (pos < 3025) {
        size_t o = ((size_t)b * 3025 + pos) * 32 + l15;
        float v = acc[i][0][r] + bv0;
        v = v > 0.f ? v : 0.f;
        unsigned short h = f2bf(v);
        ohi[o] = h; olo[o] = f2bf(v - bf2f(h));
        v = acc[i][1][r] + bv1;
        v = v > 0.f ? v : 0.f;
        h = f2bf(v);
        ohi[o + 16] = h; olo[o + 16] = f2bf(v - bf2f(h));
      }
    }
  }
}

// ---- conv2 weights [64][32][4][4] fp32 -> [tap][cout][cin] bf16 hi/lo ----
__global__ __launch_bounds__(256) void convert_w2(const float* __restrict__ w,
    unsigned short* __restrict__ hi, unsigned short* __restrict__ lo)
{
  int i = blockIdx.x * 256 + threadIdx.x;
  if (i >= 16 * 64 * 32) return;
  int tap = i >> 11, rem = i & 2047;
  int co = rem >> 5, ci = rem & 31;
  float x = w[co * 512 + ci * 16 + tap];
  unsigned short h = f2bf(x);
  hi[i] = h; lo[i] = f2bf(x - bf2f(h));
}

// ---- conv2 implicit-GEMM MFMA bf16x3 (unchanged; quarter-batch) ----
__global__ __launch_bounds__(256) void conv2_mfma(const unsigned short* __restrict__ xhi,
    const unsigned short* __restrict__ xlo, const unsigned short* __restrict__ whi,
    const unsigned short* __restrict__ wlo, const float* __restrict__ bias,
    unsigned short* __restrict__ ohi, unsigned short* __restrict__ olo, int batch0)
{
  int wv = threadIdx.x >> 6, lane = threadIdx.x & 63;
  int b = blockIdx.y;                 // local batch
  int job = blockIdx.x * 4 + wv;      // 0..43
  int mpair = job >> 1, npair = job & 1;
  int l15 = lane & 15, kg = lane >> 4;
  int pos0 = mpair * 32 + l15;
  int pos1 = pos0 + 16;
  int cp0 = pos0 > 675 ? 675 : pos0;
  int cp1 = pos1 > 675 ? 675 : pos1;
  int y0 = cp0 / 26, x0 = cp0 % 26;
  int y1 = cp1 / 26, x1 = cp1 % 26;
  size_t ibase = (size_t)b * 96800;   // 3025*32
  int co0 = npair * 32 + l15;
  int co1 = co0 + 16;
  int ib0 = co0 * 32 + kg * 8;
  int ib1 = co1 * 32 + kg * 8;
  f32x4 a00 = {0,0,0,0}, a01 = {0,0,0,0}, a10 = {0,0,0,0}, a11 = {0,0,0,0};
#pragma unroll 4
  for (int tap = 0; tap < 16; ++tap) {
    int kh = tap >> 2, kw = tap & 3;
    int ia0 = ((2 * y0 + kh) * 55 + 2 * x0 + kw) * 32 + kg * 8;
    int ia1 = ((2 * y1 + kh) * 55 + 2 * x1 + kw) * 32 + kg * 8;
    int wb = tap * 2048;
    short8 A0h = *(const short8*)(xhi + ibase + ia0);
    short8 A0l = *(const short8*)(xlo + ibase + ia0);
    short8 A1h = *(const short8*)(xhi + ibase + ia1);
    short8 A1l = *(const short8*)(xlo + ibase + ia1);
    short8 B0h = *(const short8*)(whi + wb + ib0);
    short8 B0l = *(const short8*)(wlo + wb + ib0);
    short8 B1h = *(const short8*)(whi + wb + ib1);
    short8 B1l = *(const short8*)(wlo + wb + ib1);
    a00 = __builtin_amdgcn_mfma_f32_16x16x32_bf16(A0h, B0h, a00, 0, 0, 0);
    a01 = __builtin_amdgcn_mfma_f32_16x16x32_bf16(A0h, B1h, a01, 0, 0, 0);
    a10 = __builtin_amdgcn_mfma_f32_16x16x32_bf16(A1h, B0h, a10, 0, 0, 0);
    a11 = __builtin_amdgcn_mfma_f32_16x16x32_bf16(A1h, B1h, a11, 0, 0, 0);
    a00 = __builtin_amdgcn_mfma_f32_16x16x32_bf16(A0h, B0l, a00, 0, 0, 0);
    a01 = __builtin_amdgcn_mfma_f32_16x16x32_bf16(A0h, B1l, a01, 0, 0, 0);
    a10 = __builtin_amdgcn_mfma_f32_16x16x32_bf16(A1h, B0l, a10, 0, 0, 0);
    a11 = __builtin_amdgcn_mfma_f32_16x16x32_bf16(A1h, B1l, a11, 0, 0, 0);
    a00 = __builtin_amdgcn_mfma_f32_16x16x32_bf16(A0l, B0h, a00, 0, 0, 0);
    a01 = __builtin_amdgcn_mfma_f32_16x16x32_bf16(A0l, B1h, a01, 0, 0, 0);
    a10 = __builtin_amdgcn_mfma_f32_16x16x32_bf16(A1l, B0h, a10, 0, 0, 0);
    a11 = __builtin_amdgcn_mfma_f32_16x16x32_bf16(A1l, B1h, a11, 0, 0, 0);
  }
  float bia0 = bias[co0], bia1 = bias[co1];
  size_t obase = (size_t)(batch0 + b) * 676;
#pragma unroll
  for (int r = 0; r < 4; ++r) {
    int p0 = mpair * 32 + kg * 4 + r;
    int p1 = p0 + 16;
    float v; unsigned short h;
    if (p0 < 676) {
      size_t o = (obase + p0) * 64;
      v = a00[r] + bia0; v = v > 0.f ? v : 0.f; h = f2bf(v);
      ohi[o + co0] = h; olo[o + co0] = f2bf(v - bf2f(h));
      v = a01[r] + bia1; v = v > 0.f ? v : 0.f; h = f2bf(v);
      ohi[o + co1] = h; olo[o + co1] = f2bf(v - bf2f(h));
    }
    if (p1 < 676) {
      size_t o = (obase + p1) * 64;
      v = a10[r] + bia0; v = v > 0.f ? v : 0.f; h = f2bf(v);
      ohi[o + co0] = h; olo[o + co0] = f2bf(v - bf2f(h));
      v = a11[r] + bia1; v = v > 0.f ? v : 0.f; h = f2bf(v);
      ohi[o + co1] = h; olo[o + co1] = f2bf(v - bf2f(h));
    }
  }
}

// ---- conv3 weights [cout][cin][3][3] fp32 -> [tap][cout][cin] bf16 hi/lo ----
__global__ __launch_bounds__(256) void convert_w3(const float* __restrict__ w,
    unsigned short* __restrict__ hi, unsigned short* __restrict__ lo)
{
  int i = blockIdx.x * 256 + threadIdx.x;
  if (i >= 9 * 64 * 64) return;
  int tap = i >> 12, rem = i & 4095;
  int cout = rem >> 6, cin = rem & 63;
  float x = w[cout * 576 + cin * 9 + tap];
  unsigned short h = f2bf(x);
  hi[i] = h; lo[i] = f2bf(x - bf2f(h));
}

// ---- conv3 implicit-GEMM MFMA bf16x3: wave = 48 pos x 64 cout (unchanged) ----
__global__ __launch_bounds__(256) void conv3_mfma(const unsigned short* __restrict__ xhi,
    const unsigned short* __restrict__ xlo, const unsigned short* __restrict__ whi,
    const unsigned short* __restrict__ wlo, const float* __restrict__ bias,
    unsigned short* __restrict__ bhi, unsigned short* __restrict__ blo)
{
  int wv = threadIdx.x >> 6, lane = threadIdx.x & 63;
  int b = blockIdx.y;
  int l15 = lane & 15, kg = lane >> 4;
  int posbase = blockIdx.x * 192 + wv * 48;
  int rowcol[3];
#pragma unroll
  for (int i = 0; i < 3; ++i) {
    int pos = posbase + i * 16 + l15;
    int y = pos / 24, x = pos % 24;
    rowcol[i] = (y * 26 + x) * 64;
  }
  const unsigned short* xh = xhi + (size_t)b * 43264;
  const unsigned short* xl = xlo + (size_t)b * 43264;
  int ibn[4];
#pragma unroll
  for (int nt = 0; nt < 4; ++nt) ibn[nt] = (nt * 16 + l15) * 64;
  f32x4 acc[3][4];
#pragma unroll
  for (int i = 0; i < 3; ++i)
#pragma unroll
    for (int nt = 0; nt < 4; ++nt) acc[i][nt] = (f32x4){0.f, 0.f, 0.f, 0.f};

#pragma unroll 1
  for (int tap = 0; tap < 9; ++tap) {
    int kh = tap / 3, kw = tap % 3;
    int toff = (kh * 26 + kw) * 64 + kg * 8;
    int wboff = tap * 4096 + kg * 8;
#pragma unroll
    for (int ks = 0; ks < 2; ++ks) {
      int ko = ks * 32;
      short8 Ah[3], Al[3], Bh[4], Bl[4];
#pragma unroll
      for (int i = 0; i < 3; ++i) {
        Ah[i] = *(const short8*)(xh + rowcol[i] + toff + ko);
        Al[i] = *(const short8*)(xl + rowcol[i] + toff + ko);
      }
#pragma unroll
      for (int nt = 0; nt < 4; ++nt) {
        Bh[nt] = *(const short8*)(whi + wboff + ibn[nt] + ko);
        Bl[nt] = *(const short8*)(wlo + wboff + ibn[nt] + ko);
      }
#pragma unroll
      for (int i = 0; i < 3; ++i)
#pragma unroll
        for (int nt = 0; nt < 4; ++nt) {
          acc[i][nt] = __builtin_amdgcn_mfma_f32_16x16x32_bf16(Ah[i], Bh[nt], acc[i][nt], 0, 0, 0);
          acc[i][nt] = __builtin_amdgcn_mfma_f32_16x16x32_bf16(Ah[i], Bl[nt], acc[i][nt], 0, 0, 0);
          acc[i][nt] = __builtin_amdgcn_mfma_f32_16x16x32_bf16(Al[i], Bh[nt], acc[i][nt], 0, 0, 0);
        }
    }
  }
  float bv[4];
#pragma unroll
  for (int nt = 0; nt < 4; ++nt) bv[nt] = bias[nt * 16 + l15];
  size_t ob = (size_t)b * KP;
#pragma unroll
  for (int i = 0; i < 3; ++i) {
#pragma unroll
    for (int r = 0; r < 4; ++r) {
      int pos = posbase + i * 16 + kg * 4 + r;
      size_t o = ob + (size_t)pos * 64 + l15;
#pragma unroll
      for (int nt = 0; nt < 4; ++nt) {
        float v = acc[i][nt][r] + bv[nt];
        v = v > 0.f ? v : 0.f;
        unsigned short h = f2bf(v);
        bhi[o + nt * 16] = h;
        blo[o + nt * 16] = f2bf(v - bf2f(h));
      }
    }
  }
}

// ---- fill history tail + zero pad of base planes: k in [36864, 36960), identity ----
__global__ __launch_bounds__(128) void fill_hist(const float* __restrict__ hist,
    unsigned short* __restrict__ bhi, unsigned short* __restrict__ blo)
{
  int b = blockIdx.x, t = threadIdx.x;
  int k = FEAT + t;
  if (k >= KP) return;
  float x = (k < K1) ? hist[b * HIST + t] : 0.f;
  unsigned short h = f2bf(x);
  size_t o = (size_t)b * KP + k;
  bhi[o] = h; blo[o] = f2bf(x - bf2f(h));
}

// ---- fc1 weights feat part, PERMUTED to pos-major: dst[o][pos*64+c] = w[o][c*576+pos] ----
__global__ __launch_bounds__(256) void convert_w1(const float* __restrict__ w,
    unsigned short* __restrict__ hi, unsigned short* __restrict__ lo)
{
  __shared__ float tl[64][65];
  int o = blockIdx.y;
  int p0 = blockIdx.x * 64;
  int t = threadIdx.x;
  const float* src = w + (size_t)o * K1;
  for (int e = t; e < 4096; e += 256) {
    int c = e >> 6, p = e & 63;
    tl[p][c] = src[c * 576 + p0 + p];
  }
  __syncthreads();
  size_t dbase = (size_t)o * KP;
  for (int e = t; e < 4096; e += 256) {
    int p = e >> 6, c = e & 63;
    float x = tl[p][c];
    unsigned short h = f2bf(x);
    size_t d = dbase + (size_t)(p0 + p) * 64 + c;
    hi[d] = h; lo[d] = f2bf(x - bf2f(h));
  }
}

// ---- fc1 weights history tail [36864, 36960), identity mapping ----
__global__ __launch_bounds__(128) void convert_w1_tail(const float* __restrict__ w,
    unsigned short* __restrict__ hi, unsigned short* __restrict__ lo)
{
  int o = blockIdx.x, t = threadIdx.x;
  int k = FEAT + t;
  if (k >= KP) return;
  float x = (k < K1) ? w[(size_t)o * K1 + k] : 0.f;
  unsigned short h = f2bf(x);
  size_t p = (size_t)o * KP + k;
  hi[p] = h; lo[p] = f2bf(x - bf2f(h));
}

// ---------------- fc2 weight transpose: [256][128] -> [128][256] ----------------
__global__ __launch_bounds__(256) void transpose_fc2(const float* __restrict__ w,
                                                     float* __restrict__ wT)
{
  int idx = blockIdx.x * 256 + threadIdx.x;
  if (idx < 128 * 256) {
    int i = idx >> 8, j = idx & 255;
    wT[idx] = w[j * 128 + i];
  }
}

// ---- fc1 MFMA bf16x3 split-K (unchanged) ----
__global__ __launch_bounds__(256) void fc1_mfma(const unsigned short* __restrict__ bhi,
    const unsigned short* __restrict__ blo, const unsigned short* __restrict__ whi,
    const unsigned short* __restrict__ wlo, float* __restrict__ part)
{
  int w = threadIdx.x >> 6, lane = threadIdx.x & 63;
  int job = blockIdx.x * 4 + w;        // 0..63
  int mt2 = job & 7, nt = job >> 3;
  int ks = blockIdx.y;                 // 0..32
  int k0 = ks * 35 * 32;
  int l15 = lane & 15, kg = lane >> 4;
  int s0 = mt2 * 32 + l15;
  int o  = nt * 16 + l15;
  const unsigned short* pa0h = bhi + (size_t)s0 * KP + k0 + kg * 8;
  const unsigned short* pa1h = pa0h + (size_t)16 * KP;
  const unsigned short* pa0l = blo + (size_t)s0 * KP + k0 + kg * 8;
  const unsigned short* pa1l = pa0l + (size_t)16 * KP;
  const unsigned short* pbh  = whi + (size_t)o * KP + k0 + kg * 8;
  const unsigned short* pbl  = wlo + (size_t)o * KP + k0 + kg * 8;
  f32x4 acc0 = {0.f, 0.f, 0.f, 0.f}, acc1 = {0.f, 0.f, 0.f, 0.f};
#pragma unroll 1
  for (int i = 0; i < 35; ++i) {
    short8 a0h = *(const short8*)pa0h;
    short8 a1h = *(const short8*)pa1h;
    short8 a0l = *(const short8*)pa0l;
    short8 a1l = *(const short8*)pa1l;
    short8 bh  = *(const short8*)pbh;
    short8 bl  = *(const short8*)pbl;
    acc0 = __builtin_amdgcn_mfma_f32_16x16x32_bf16(a0h, bh, acc0, 0, 0, 0);
    acc1 = __builtin_amdgcn_mfma_f32_16x16x32_bf16(a1h, bh, acc1, 0, 0, 0);
    acc0 = __builtin_amdgcn_mfma_f32_16x16x32_bf16(a0h, bl, acc0, 0, 0, 0);
    acc1 = __builtin_amdgcn_mfma_f32_16x16x32_bf16(a1h, bl, acc1, 0, 0, 0);
    acc0 = __builtin_amdgcn_mfma_f32_16x16x32_bf16(a0l, bh, acc0, 0, 0, 0);
    acc1 = __builtin_amdgcn_mfma_f32_16x16x32_bf16(a1l, bh, acc1, 0, 0, 0);
    pa0h += 32; pa1h += 32; pa0l += 32; pa1l += 32; pbh += 32; pbl += 32;
  }
  float* pp0 = part + (((size_t)ks * 64 + job) * 2) * 256;
  float* pp1 = pp0 + 256;
#pragma unroll
  for (int r = 0; r < 4; ++r) {
    pp0[r * 64 + lane] = acc0[r];
    pp1[r * 64 + lane] = acc1[r];
  }
}

// ---- fixed-order split-K reduce ----
__global__ __launch_bounds__(256) void fc1_reduce(const float* __restrict__ part,
                                                  float* __restrict__ h1)
{
  int i = blockIdx.x * 256 + threadIdx.x;
  if (i >= 32768) return;
  int s = i >> 7, o = i & 127;
  int mt2 = s >> 5, ti = (s >> 4) & 1, nt = o >> 4;
  int job = nt * 8 + mt2;
  int r = s & 15, c = o & 15;
  int off = (job * 2 + ti) * 256 + (r & 3) * 64 + ((r >> 2) << 4) + c;
  float sum = 0.f;
#pragma unroll 1
  for (int ks = 0; ks < 33; ++ks) sum += part[(size_t)ks * 32768 + off];
  h1[i] = sum;
}

// ---------------- SNN simulation (unchanged) ----------------
__global__ __launch_bounds__(256) void snn_ker(const float* __restrict__ h1,
    const float* __restrict__ b1, const float* __restrict__ w2T,
    const float* __restrict__ b2p, const float* __restrict__ w3,
    const float* __restrict__ b3p, float* __restrict__ out)
{
  int b = blockIdx.x, t = threadIdx.x;
  __shared__ float spk1l[128];
  __shared__ float part[4][9];
  float h1v = 0.f;
  if (t < 128) h1v = h1[b * 128 + t] + b1[t];
  float b2 = b2p[t];
  float w3r[9];
#pragma unroll
  for (int j = 0; j < 9; ++j) w3r[j] = w3[j * 256 + t];
  float mem1 = 0.f, syn1 = 0.f, mem2 = 0.f, syn2 = 0.f;
  float syn3[9], mem3[9], pot[9];
#pragma unroll
  for (int j = 0; j < 9; ++j) { syn3[j] = 0.f; mem3[j] = 0.f; pot[j] = 0.f; }

#pragma unroll 1
  for (int step = 0; step < 10; ++step) {
    if (t < 128) {
      syn1 = ALPHA * syn1 + h1v;
      mem1 = BETA * mem1 + syn1;
      float s = (mem1 > 1.0f) ? 1.f : 0.f;
      spk1l[t] = s;
      mem1 -= s;
    }
    __syncthreads();
    float h2 = b2;
    for (int i = 0; i < 128; ++i) {
      if (spk1l[i] != 0.f) h2 += w2T[i * 256 + t];
    }
    syn2 = ALPHA * syn2 + h2;
    mem2 = BETA * mem2 + syn2;
    float s2 = (mem2 > 1.0f) ? 1.f : 0.f;
    mem2 -= s2;

    float v[9];
#pragma unroll
    for (int j = 0; j < 9; ++j) v[j] = s2 * w3r[j];
#pragma unroll
    for (int j = 0; j < 9; ++j) {
      v[j] += __shfl_down(v[j], 32);
      v[j] += __shfl_down(v[j], 16);
      v[j] += __shfl_down(v[j], 8);
      v[j] += __shfl_down(v[j], 4);
      v[j] += __shfl_down(v[j], 2);
      v[j] += __shfl_down(v[j], 1);
    }
    if ((t & 63) == 0) {
#pragma unroll
      for (int j = 0; j < 9; ++j) part[t >> 6][j] = v[j];
    }
    __syncthreads();
    if (t == 0) {
#pragma unroll
      for (int j = 0; j < 9; ++j) {
        float h3 = part[0][j] + part[1][j] + part[2][j] + part[3][j] + b3p[j];
        syn3[j] = ALPHA * syn3[j] + h3;
        mem3[j] = BETA * mem3[j] + syn3[j];
        pot[j] += mem3[j];
      }
    }
  }
  if (t == 0) {
#pragma unroll
    for (int j = 0; j < 9; ++j) out[b * 9 + j] = pot[j] / 10.0f;
  }
}

// ---------------- host ----------------
extern "C" void kernel_launch(void* const* d_in, const int* in_sizes, int n_in,
                              void* d_out, int out_size, void* d_ws, size_t ws_size,
                              hipStream_t stream)
{
  const float* state = (const float*)d_in[0];
  const float* hist  = (const float*)d_in[1];
  const float* c1w   = (const float*)d_in[2];
  const float* c1b   = (const float*)d_in[3];
  const float* c2w   = (const float*)d_in[4];
  const float* c2b   = (const float*)d_in[5];
  const float* c3w   = (const float*)d_in[6];
  const float* c3b   = (const float*)d_in[7];
  const float* f1w   = (const float*)d_in[8];
  const float* f1b   = (const float*)d_in[9];
  const float* f2w   = (const float*)d_in[10];
  const float* f2b   = (const float*)d_in[11];
  const float* f3w   = (const float*)d_in[12];
  const float* f3b   = (const float*)d_in[13];
  float* out = (float*)d_out;
  float* ws  = (float*)d_ws;

  // workspace (float offsets), peak 27,045,888 floats (108.2 MB):
  //   sthi [0, 4,816,896) stlo [4,816,896, 9,633,792)       (quarter-batch state planes)
  //   c1hi [9,633,792, 12,731,392) c1lo [12,731,392, 15,828,992)  (quarter-batch)
  //   w1chi [15,828,992, 15,832,064) w1clo [15,832,064, 15,835,136)
  //   c2hi [15,835,136, 21,372,928) c2lo [21,372,928, 26,910,720) (full batch)
  //   w2hi [26,910,720, 26,927,104) w2lo [26,927,104, 26,943,488)
  //   w3hi [26,943,488, 26,961,920) w3lo [26,961,920, 26,980,352)
  //   h1 [26,980,352, 27,013,120) wT2 [27,013,120, 27,045,888)
  //   AFTER conv passes (state/c1/w1c dead):
  //   base_hi [0, 4,730,880) base_lo [4,730,880, 9,461,760)
  //   w1_hi [9,461,760, 11,827,200) w1_lo [11,827,200, 14,192,640)
  //   partb [14,192,640, 15,273,984)
  unsigned short* sthi    = (unsigned short*)(ws);
  unsigned short* stlo    = (unsigned short*)(ws + 4816896);
  unsigned short* c1hi    = (unsigned short*)(ws + 9633792);
  unsigned short* c1lo    = (unsigned short*)(ws + 12731392);
  unsigned short* w1chi   = (unsigned short*)(ws + 15828992);
  unsigned short* w1clo   = (unsigned short*)(ws + 15832064);
  unsigned short* c2hi    = (unsigned short*)(ws + 15835136);
  unsigned short* c2lo    = (unsigned short*)(ws + 21372928);
  unsigned short* w2_hi   = (unsigned short*)(ws + 26910720);
  unsigned short* w2_lo   = (unsigned short*)(ws + 26927104);
  unsigned short* w3_hi   = (unsigned short*)(ws + 26943488);
  unsigned short* w3_lo   = (unsigned short*)(ws + 26961920);
  float* h1buf    = ws + 26980352;
  float* wT2      = ws + 27013120;
  unsigned short* base_hi = (unsigned short*)(ws);
  unsigned short* base_lo = (unsigned short*)(ws + 4730880);
  unsigned short* w1_hi   = (unsigned short*)(ws + 9461760);
  unsigned short* w1_lo   = (unsigned short*)(ws + 11827200);
  float* partb    = ws + 14192640;

  convert_w1c<<<dim3(24), 256, 0, stream>>>(c1w, w1chi, w1clo);
  convert_w2<<<dim3(128), 256, 0, stream>>>(c2w, w2_hi, w2_lo);
  convert_w3<<<dim3(144), 256, 0, stream>>>(c3w, w3_hi, w3_lo);
  // quarter-batch conv1 -> conv2 passes
  for (int q = 0; q < 4; ++q) {
    convert_state<<<dim3(4704), 256, 0, stream>>>(state + (size_t)q * 9633792, sthi, stlo);
    conv1_mfma<<<dim3(16, 64), 256, 0, stream>>>(sthi, stlo, w1chi, w1clo, c1b, c1hi, c1lo);
    conv2_mfma<<<dim3(11, 64), 256, 0, stream>>>(c1hi, c1lo, w2_hi, w2_lo, c2b,
                                                 c2hi, c2lo, q * 64);
  }
  // state/c1/w1c dead -> region reused for base planes + w1 planes + partb
  convert_w1<<<dim3(9, 128), 256, 0, stream>>>(f1w, w1_hi, w1_lo);
  convert_w1_tail<<<dim3(128), 128, 0, stream>>>(f1w, w1_hi, w1_lo);
  fill_hist<<<dim3(256), 128, 0, stream>>>(hist, base_hi, base_lo);
  conv3_mfma<<<dim3(3, 256), 256, 0, stream>>>(c2hi, c2lo, w3_hi, w3_lo, c3b,
                                               base_hi, base_lo);
  transpose_fc2<<<dim3(128), 256, 0, stream>>>(f2w, wT2);
  fc1_mfma<<<dim3(16, 33), 256, 0, stream>>>(base_hi, base_lo, w1_hi, w1_lo, partb);
  fc1_reduce<<<dim3(128), 256, 0, stream>>>(partb, h1buf);
  snn_ker<<<dim3(256), 256, 0, stream>>>(h1buf, f1b, wT2, f2b, f3w, f3b, out);
}

// Round 11
// 466.666 us; speedup vs baseline: 2.3553x; 1.2014x over previous
//
#include <hip/hip_runtime.h>
#include <cstddef>
#include <cstdint>

#define ALPHA 0.9f
#define BETA  0.8f

// ---------------- sizes ----------------
// conv1: 32x3x8x8 s4 -> [256,32,55,55]   (MFMA implicit GEMM bf16x4, quarter-batch)
// conv2: 64x32x4x4 s2 -> [256,64,26,26]  (MFMA implicit GEMM bf16x3, channels-last)
// conv3: 64x64x3x3 s1 -> [256,64,24,24]  (MFMA implicit GEMM bf16x3 -> base planes, pos-major)
// base k-index is PERMUTED: feat k = pos*64+cout (w1 planes permuted to match);
// history tail [36864,36954) identity. KP = 36960 (= 33*35*32)
#define FEAT   36864
#define HIST   90
#define K1     36954
#define KP     36960

typedef __attribute__((ext_vector_type(8))) short short8;
typedef __attribute__((ext_vector_type(4))) float f32x4;
typedef __attribute__((ext_vector_type(2))) int int2v;

__device__ __forceinline__ unsigned short f2bf(float x) {
  unsigned u = __float_as_uint(x);
  return (unsigned short)((u + 0x7FFFu + ((u >> 16) & 1u)) >> 16);
}
__device__ __forceinline__ float bf2f(unsigned short h) {
  return __uint_as_float(((unsigned)h) << 16);
}
// 8-short load from an 8-byte-aligned (not necessarily 16B) address
__device__ __forceinline__ short8 ld8u(const unsigned short* p) {
  int2v a = *(const int2v*)(p);
  int2v b = *(const int2v*)(p + 4);
  union { int2v i[2]; short8 s; } u;
  u.i[0] = a; u.i[1] = b;
  return u.s;
}

// ---- state fp32 -> bf16 hi/lo planes (quarter batch: 64*3*224*224 = 9,633,792 elems) ----
__global__ __launch_bounds__(256) void convert_state(const float* __restrict__ in,
    unsigned short* __restrict__ hi, unsigned short* __restrict__ lo)
{
  size_t idx = ((size_t)blockIdx.x * 256 + threadIdx.x) * 8;
  if (idx >= 9633792) return;
  const float4 f0 = *(const float4*)(in + idx);
  const float4 f1 = *(const float4*)(in + idx + 4);
  float v[8] = {f0.x, f0.y, f0.z, f0.w, f1.x, f1.y, f1.z, f1.w};
  short8 h8, l8;
#pragma unroll
  for (int q = 0; q < 8; ++q) {
    unsigned short h = f2bf(v[q]);
    h8[q] = (short)h; l8[q] = (short)f2bf(v[q] - bf2f(h));
  }
  *(short8*)(hi + idx) = h8;
  *(short8*)(lo + idx) = l8;
}

// ---- conv1 weights [32][3][8][8] -> [pair=c*8+kh][cout][kw] bf16 hi/lo ----
__global__ __launch_bounds__(256) void convert_w1c(const float* __restrict__ w,
    unsigned short* __restrict__ hi, unsigned short* __restrict__ lo)
{
  int i = blockIdx.x * 256 + threadIdx.x;
  if (i >= 6144) return;
  int kw = i & 7, rest = i >> 3;
  int cout = rest & 31, pair = rest >> 5;
  int c = pair >> 3, kh = pair & 7;
  float x = w[((cout * 3 + c) * 8 + kh) * 8 + kw];
  unsigned short h = f2bf(x);
  hi[i] = h; lo[i] = f2bf(x - bf2f(h));
}

// ---- conv1 implicit-GEMM MFMA bf16x4 (all 4 products): wave = 48 pos x 32 cout ----
__global__ __launch_bounds__(256) void conv1_mfma(const unsigned short* __restrict__ xhi,
    const unsigned short* __restrict__ xlo, const unsigned short* __restrict__ whi,
    const unsigned short* __restrict__ wlo, const float* __restrict__ bias,
    unsigned short* __restrict__ ohi, unsigned short* __restrict__ olo)
{
  int wv = threadIdx.x >> 6, lane = threadIdx.x & 63;
  int b = blockIdx.y;             // local batch 0..63
  int l15 = lane & 15, kg = lane >> 4;
  int posbase = blockIdx.x * 192 + wv * 48;
  int rowb[3];
#pragma unroll
  for (int i = 0; i < 3; ++i) {
    int pos = posbase + i * 16 + l15;
    int cp = pos > 3024 ? 3024 : pos;
    int y = cp / 55, x = cp % 55;
    rowb[i] = (y * 4) * 224 + x * 4;
  }
  const unsigned short* xh = xhi + (size_t)b * 150528;
  const unsigned short* xl = xlo + (size_t)b * 150528;
  f32x4 acc[3][2];
#pragma unroll
  for (int i = 0; i < 3; ++i) {
    acc[i][0] = (f32x4){0.f, 0.f, 0.f, 0.f};
    acc[i][1] = (f32x4){0.f, 0.f, 0.f, 0.f};
  }
#pragma unroll 2
  for (int s = 0; s < 6; ++s) {
    int pair = s * 4 + kg;
    int c = pair >> 3, kh = pair & 7;
    int aoff = c * 50176 + kh * 224;
    short8 Ah[3], Al[3], Bh[2], Bl[2];
#pragma unroll
    for (int i = 0; i < 3; ++i) {
      Ah[i] = ld8u(xh + aoff + rowb[i]);
      Al[i] = ld8u(xl + aoff + rowb[i]);
    }
    int wb = (pair * 32 + l15) * 8;
#pragma unroll
    for (int nt = 0; nt < 2; ++nt) {
      Bh[nt] = *(const short8*)(whi + wb + nt * 128);
      Bl[nt] = *(const short8*)(wlo + wb + nt * 128);
    }
#pragma unroll
    for (int i = 0; i < 3; ++i)
#pragma unroll
      for (int nt = 0; nt < 2; ++nt) {
        acc[i][nt] = __builtin_amdgcn_mfma_f32_16x16x32_bf16(Ah[i], Bh[nt], acc[i][nt], 0, 0, 0);
        acc[i][nt] = __builtin_amdgcn_mfma_f32_16x16x32_bf16(Ah[i], Bl[nt], acc[i][nt], 0, 0, 0);
        acc[i][nt] = __builtin_amdgcn_mfma_f32_16x16x32_bf16(Al[i], Bh[nt], acc[i][nt], 0, 0, 0);
        acc[i][nt] = __builtin_amdgcn_mfma_f32_16x16x32_bf16(Al[i], Bl[nt], acc[i][nt], 0, 0, 0);
      }
  }
  float bv0 = bias[l15], bv1 = bias[16 + l15];
#pragma unroll
  for (int i = 0; i < 3; ++i) {
#pragma unroll
    for (int r = 0; r < 4; ++r) {
      int pos = posbase + i * 16 + kg * 4 + r;
      if (pos < 3025) {
        size_t o = ((size_t)b * 3025 + pos) * 32 + l15;
        float v = acc[i][0][r] + bv0;
        v = v > 0.f ? v : 0.f;
        unsigned short h = f2bf(v);
        ohi[o] = h; olo[o] = f2bf(v - bf2f(h));
        v = acc[i][1][r] + bv1;
        v = v > 0.f ? v : 0.f;
        h = f2bf(v);
        ohi[o + 16] = h; olo[o + 16] = f2bf(v - bf2f(h));
      }
    }
  }
}

// ---- conv2 weights [64][32][4][4] fp32 -> [tap][cout][cin] bf16 hi/lo ----
__global__ __launch_bounds__(256) void convert_w2(const float* __restrict__ w,
    unsigned short* __restrict__ hi, unsigned short* __restrict__ lo)
{
  int i = blockIdx.x * 256 + threadIdx.x;
  if (i >= 16 * 64 * 32) return;
  int tap = i >> 11, rem = i & 2047;
  int co = rem >> 5, ci = rem & 31;
  float x = w[co * 512 + ci * 16 + tap];
  unsigned short h = f2bf(x);
  hi[i] = h; lo[i] = f2bf(x - bf2f(h));
}

// ---- conv2 implicit-GEMM MFMA bf16x3 (unchanged; quarter-batch) ----
__global__ __launch_bounds__(256) void conv2_mfma(const unsigned short* __restrict__ xhi,
    const unsigned short* __restrict__ xlo, const unsigned short* __restrict__ whi,
    const unsigned short* __restrict__ wlo, const float* __restrict__ bias,
    unsigned short* __restrict__ ohi, unsigned short* __restrict__ olo, int batch0)
{
  int wv = threadIdx.x >> 6, lane = threadIdx.x & 63;
  int b = blockIdx.y;                 // local batch
  int job = blockIdx.x * 4 + wv;      // 0..43
  int mpair = job >> 1, npair = job & 1;
  int l15 = lane & 15, kg = lane >> 4;
  int pos0 = mpair * 32 + l15;
  int pos1 = pos0 + 16;
  int cp0 = pos0 > 675 ? 675 : pos0;
  int cp1 = pos1 > 675 ? 675 : pos1;
  int y0 = cp0 / 26, x0 = cp0 % 26;
  int y1 = cp1 / 26, x1 = cp1 % 26;
  size_t ibase = (size_t)b * 96800;   // 3025*32
  int co0 = npair * 32 + l15;
  int co1 = co0 + 16;
  int ib0 = co0 * 32 + kg * 8;
  int ib1 = co1 * 32 + kg * 8;
  f32x4 a00 = {0,0,0,0}, a01 = {0,0,0,0}, a10 = {0,0,0,0}, a11 = {0,0,0,0};
#pragma unroll 4
  for (int tap = 0; tap < 16; ++tap) {
    int kh = tap >> 2, kw = tap & 3;
    int ia0 = ((2 * y0 + kh) * 55 + 2 * x0 + kw) * 32 + kg * 8;
    int ia1 = ((2 * y1 + kh) * 55 + 2 * x1 + kw) * 32 + kg * 8;
    int wb = tap * 2048;
    short8 A0h = *(const short8*)(xhi + ibase + ia0);
    short8 A0l = *(const short8*)(xlo + ibase + ia0);
    short8 A1h = *(const short8*)(xhi + ibase + ia1);
    short8 A1l = *(const short8*)(xlo + ibase + ia1);
    short8 B0h = *(const short8*)(whi + wb + ib0);
    short8 B0l = *(const short8*)(wlo + wb + ib0);
    short8 B1h = *(const short8*)(whi + wb + ib1);
    short8 B1l = *(const short8*)(wlo + wb + ib1);
    a00 = __builtin_amdgcn_mfma_f32_16x16x32_bf16(A0h, B0h, a00, 0, 0, 0);
    a01 = __builtin_amdgcn_mfma_f32_16x16x32_bf16(A0h, B1h, a01, 0, 0, 0);
    a10 = __builtin_amdgcn_mfma_f32_16x16x32_bf16(A1h, B0h, a10, 0, 0, 0);
    a11 = __builtin_amdgcn_mfma_f32_16x16x32_bf16(A1h, B1h, a11, 0, 0, 0);
    a00 = __builtin_amdgcn_mfma_f32_16x16x32_bf16(A0h, B0l, a00, 0, 0, 0);
    a01 = __builtin_amdgcn_mfma_f32_16x16x32_bf16(A0h, B1l, a01, 0, 0, 0);
    a10 = __builtin_amdgcn_mfma_f32_16x16x32_bf16(A1h, B0l, a10, 0, 0, 0);
    a11 = __builtin_amdgcn_mfma_f32_16x16x32_bf16(A1h, B1l, a11, 0, 0, 0);
    a00 = __builtin_amdgcn_mfma_f32_16x16x32_bf16(A0l, B0h, a00, 0, 0, 0);
    a01 = __builtin_amdgcn_mfma_f32_16x16x32_bf16(A0l, B1h, a01, 0, 0, 0);
    a10 = __builtin_amdgcn_mfma_f32_16x16x32_bf16(A1l, B0h, a10, 0, 0, 0);
    a11 = __builtin_amdgcn_mfma_f32_16x16x32_bf16(A1l, B1h, a11, 0, 0, 0);
  }
  float bia0 = bias[co0], bia1 = bias[co1];
  size_t obase = (size_t)(batch0 + b) * 676;
#pragma unroll
  for (int r = 0; r < 4; ++r) {
    int p0 = mpair * 32 + kg * 4 + r;
    int p1 = p0 + 16;
    float v; unsigned short h;
    if (p0 < 676) {
      size_t o = (obase + p0) * 64;
      v = a00[r] + bia0; v = v > 0.f ? v : 0.f; h = f2bf(v);
      ohi[o + co0] = h; olo[o + co0] = f2bf(v - bf2f(h));
      v = a01[r] + bia1; v = v > 0.f ? v : 0.f; h = f2bf(v);
      ohi[o + co1] = h; olo[o + co1] = f2bf(v - bf2f(h));
    }
    if (p1 < 676) {
      size_t o = (obase + p1) * 64;
      v = a10[r] + bia0; v = v > 0.f ? v : 0.f; h = f2bf(v);
      ohi[o + co0] = h; olo[o + co0] = f2bf(v - bf2f(h));
      v = a11[r] + bia1; v = v > 0.f ? v : 0.f; h = f2bf(v);
      ohi[o + co1] = h; olo[o + co1] = f2bf(v - bf2f(h));
    }
  }
}

// ---- conv3 weights [cout][cin][3][3] fp32 -> [tap][cout][cin] bf16 hi/lo ----
__global__ __launch_bounds__(256) void convert_w3(const float* __restrict__ w,
    unsigned short* __restrict__ hi, unsigned short* __restrict__ lo)
{
  int i = blockIdx.x * 256 + threadIdx.x;
  if (i >= 9 * 64 * 64) return;
  int tap = i >> 12, rem = i & 4095;
  int cout = rem >> 6, cin = rem & 63;
  float x = w[cout * 576 + cin * 9 + tap];
  unsigned short h = f2bf(x);
  hi[i] = h; lo[i] = f2bf(x - bf2f(h));
}

// ---- conv3 implicit-GEMM MFMA bf16x3: wave = 48 pos x 64 cout (unchanged) ----
__global__ __launch_bounds__(256) void conv3_mfma(const unsigned short* __restrict__ xhi,
    const unsigned short* __restrict__ xlo, const unsigned short* __restrict__ whi,
    const unsigned short* __restrict__ wlo, const float* __restrict__ bias,
    unsigned short* __restrict__ bhi, unsigned short* __restrict__ blo)
{
  int wv = threadIdx.x >> 6, lane = threadIdx.x & 63;
  int b = blockIdx.y;
  int l15 = lane & 15, kg = lane >> 4;
  int posbase = blockIdx.x * 192 + wv * 48;
  int rowcol[3];
#pragma unroll
  for (int i = 0; i < 3; ++i) {
    int pos = posbase + i * 16 + l15;
    int y = pos / 24, x = pos % 24;
    rowcol[i] = (y * 26 + x) * 64;
  }
  const unsigned short* xh = xhi + (size_t)b * 43264;
  const unsigned short* xl = xlo + (size_t)b * 43264;
  int ibn[4];
#pragma unroll
  for (int nt = 0; nt < 4; ++nt) ibn[nt] = (nt * 16 + l15) * 64;
  f32x4 acc[3][4];
#pragma unroll
  for (int i = 0; i < 3; ++i)
#pragma unroll
    for (int nt = 0; nt < 4; ++nt) acc[i][nt] = (f32x4){0.f, 0.f, 0.f, 0.f};

#pragma unroll 1
  for (int tap = 0; tap < 9; ++tap) {
    int kh = tap / 3, kw = tap % 3;
    int toff = (kh * 26 + kw) * 64 + kg * 8;
    int wboff = tap * 4096 + kg * 8;
#pragma unroll
    for (int ks = 0; ks < 2; ++ks) {
      int ko = ks * 32;
      short8 Ah[3], Al[3], Bh[4], Bl[4];
#pragma unroll
      for (int i = 0; i < 3; ++i) {
        Ah[i] = *(const short8*)(xh + rowcol[i] + toff + ko);
        Al[i] = *(const short8*)(xl + rowcol[i] + toff + ko);
      }
#pragma unroll
      for (int nt = 0; nt < 4; ++nt) {
        Bh[nt] = *(const short8*)(whi + wboff + ibn[nt] + ko);
        Bl[nt] = *(const short8*)(wlo + wboff + ibn[nt] + ko);
      }
#pragma unroll
      for (int i = 0; i < 3; ++i)
#pragma unroll
        for (int nt = 0; nt < 4; ++nt) {
          acc[i][nt] = __builtin_amdgcn_mfma_f32_16x16x32_bf16(Ah[i], Bh[nt], acc[i][nt], 0, 0, 0);
          acc[i][nt] = __builtin_amdgcn_mfma_f32_16x16x32_bf16(Ah[i], Bl[nt], acc[i][nt], 0, 0, 0);
          acc[i][nt] = __builtin_amdgcn_mfma_f32_16x16x32_bf16(Al[i], Bh[nt], acc[i][nt], 0, 0, 0);
        }
    }
  }
  float bv[4];
#pragma unroll
  for (int nt = 0; nt < 4; ++nt) bv[nt] = bias[nt * 16 + l15];
  size_t ob = (size_t)b * KP;
#pragma unroll
  for (int i = 0; i < 3; ++i) {
#pragma unroll
    for (int r = 0; r < 4; ++r) {
      int pos = posbase + i * 16 + kg * 4 + r;
      size_t o = ob + (size_t)pos * 64 + l15;
#pragma unroll
      for (int nt = 0; nt < 4; ++nt) {
        float v = acc[i][nt][r] + bv[nt];
        v = v > 0.f ? v : 0.f;
        unsigned short h = f2bf(v);
        bhi[o + nt * 16] = h;
        blo[o + nt * 16] = f2bf(v - bf2f(h));
      }
    }
  }
}

// ---- fill history tail + zero pad of base planes: k in [36864, 36960), identity ----
__global__ __launch_bounds__(128) void fill_hist(const float* __restrict__ hist,
    unsigned short* __restrict__ bhi, unsigned short* __restrict__ blo)
{
  int b = blockIdx.x, t = threadIdx.x;
  int k = FEAT + t;
  if (k >= KP) return;
  float x = (k < K1) ? hist[b * HIST + t] : 0.f;
  unsigned short h = f2bf(x);
  size_t o = (size_t)b * KP + k;
  bhi[o] = h; blo[o] = f2bf(x - bf2f(h));
}

// ---- fc1 weights feat part, PERMUTED to pos-major: dst[o][pos*64+c] = w[o][c*576+pos] ----
__global__ __launch_bounds__(256) void convert_w1(const float* __restrict__ w,
    unsigned short* __restrict__ hi, unsigned short* __restrict__ lo)
{
  __shared__ float tl[64][65];
  int o = blockIdx.y;
  int p0 = blockIdx.x * 64;
  int t = threadIdx.x;
  const float* src = w + (size_t)o * K1;
  for (int e = t; e < 4096; e += 256) {
    int c = e >> 6, p = e & 63;
    tl[p][c] = src[c * 576 + p0 + p];
  }
  __syncthreads();
  size_t dbase = (size_t)o * KP;
  for (int e = t; e < 4096; e += 256) {
    int p = e >> 6, c = e & 63;
    float x = tl[p][c];
    unsigned short h = f2bf(x);
    size_t d = dbase + (size_t)(p0 + p) * 64 + c;
    hi[d] = h; lo[d] = f2bf(x - bf2f(h));
  }
}

// ---- fc1 weights history tail [36864, 36960), identity mapping ----
__global__ __launch_bounds__(128) void convert_w1_tail(const float* __restrict__ w,
    unsigned short* __restrict__ hi, unsigned short* __restrict__ lo)
{
  int o = blockIdx.x, t = threadIdx.x;
  int k = FEAT + t;
  if (k >= KP) return;
  float x = (k < K1) ? w[(size_t)o * K1 + k] : 0.f;
  unsigned short h = f2bf(x);
  size_t p = (size_t)o * KP + k;
  hi[p] = h; lo[p] = f2bf(x - bf2f(h));
}

// ---------------- fc2 weight transpose: [256][128] -> [128][256] ----------------
__global__ __launch_bounds__(256) void transpose_fc2(const float* __restrict__ w,
                                                     float* __restrict__ wT)
{
  int idx = blockIdx.x * 256 + threadIdx.x;
  if (idx < 128 * 256) {
    int i = idx >> 8, j = idx & 255;
    wT[idx] = w[j * 128 + i];
  }
}

// ---- fc1 MFMA bf16x3 split-K (unchanged) ----
__global__ __launch_bounds__(256) void fc1_mfma(const unsigned short* __restrict__ bhi,
    const unsigned short* __restrict__ blo, const unsigned short* __restrict__ whi,
    const unsigned short* __restrict__ wlo, float* __restrict__ part)
{
  int w = threadIdx.x >> 6, lane = threadIdx.x & 63;
  int job = blockIdx.x * 4 + w;        // 0..63
  int mt2 = job & 7, nt = job >> 3;
  int ks = blockIdx.y;                 // 0..32
  int k0 = ks * 35 * 32;
  int l15 = lane & 15, kg = lane >> 4;
  int s0 = mt2 * 32 + l15;
  int o  = nt * 16 + l15;
  const unsigned short* pa0h = bhi + (size_t)s0 * KP + k0 + kg * 8;
  const unsigned short* pa1h = pa0h + (size_t)16 * KP;
  const unsigned short* pa0l = blo + (size_t)s0 * KP + k0 + kg * 8;
  const unsigned short* pa1l = pa0l + (size_t)16 * KP;
  const unsigned short* pbh  = whi + (size_t)o * KP + k0 + kg * 8;
  const unsigned short* pbl  = wlo + (size_t)o * KP + k0 + kg * 8;
  f32x4 acc0 = {0.f, 0.f, 0.f, 0.f}, acc1 = {0.f, 0.f, 0.f, 0.f};
#pragma unroll 1
  for (int i = 0; i < 35; ++i) {
    short8 a0h = *(const short8*)pa0h;
    short8 a1h = *(const short8*)pa1h;
    short8 a0l = *(const short8*)pa0l;
    short8 a1l = *(const short8*)pa1l;
    short8 bh  = *(const short8*)pbh;
    short8 bl  = *(const short8*)pbl;
    acc0 = __builtin_amdgcn_mfma_f32_16x16x32_bf16(a0h, bh, acc0, 0, 0, 0);
    acc1 = __builtin_amdgcn_mfma_f32_16x16x32_bf16(a1h, bh, acc1, 0, 0, 0);
    acc0 = __builtin_amdgcn_mfma_f32_16x16x32_bf16(a0h, bl, acc0, 0, 0, 0);
    acc1 = __builtin_amdgcn_mfma_f32_16x16x32_bf16(a1h, bl, acc1, 0, 0, 0);
    acc0 = __builtin_amdgcn_mfma_f32_16x16x32_bf16(a0l, bh, acc0, 0, 0, 0);
    acc1 = __builtin_amdgcn_mfma_f32_16x16x32_bf16(a1l, bh, acc1, 0, 0, 0);
    pa0h += 32; pa1h += 32; pa0l += 32; pa1l += 32; pbh += 32; pbl += 32;
  }
  float* pp0 = part + (((size_t)ks * 64 + job) * 2) * 256;
  float* pp1 = pp0 + 256;
#pragma unroll
  for (int r = 0; r < 4; ++r) {
    pp0[r * 64 + lane] = acc0[r];
    pp1[r * 64 + lane] = acc1[r];
  }
}

// ---- fixed-order split-K reduce ----
__global__ __launch_bounds__(256) void fc1_reduce(const float* __restrict__ part,
                                                  float* __restrict__ h1)
{
  int i = blockIdx.x * 256 + threadIdx.x;
  if (i >= 32768) return;
  int s = i >> 7, o = i & 127;
  int mt2 = s >> 5, ti = (s >> 4) & 1, nt = o >> 4;
  int job = nt * 8 + mt2;
  int r = s & 15, c = o & 15;
  int off = (job * 2 + ti) * 256 + (r & 3) * 64 + ((r >> 2) << 4) + c;
  float sum = 0.f;
#pragma unroll 1
  for (int ks = 0; ks < 33; ++ks) sum += part[(size_t)ks * 32768 + off];
  h1[i] = sum;
}

// ---------------- SNN simulation: branchless unrolled fc2 matvec ----------------
__global__ __launch_bounds__(256) void snn_ker(const float* __restrict__ h1,
    const float* __restrict__ b1, const float* __restrict__ w2T,
    const float* __restrict__ b2p, const float* __restrict__ w3,
    const float* __restrict__ b3p, float* __restrict__ out)
{
  int b = blockIdx.x, t = threadIdx.x;
  __shared__ float spk1l[128];
  __shared__ float part[4][9];
  float h1v = 0.f;
  if (t < 128) h1v = h1[b * 128 + t] + b1[t];
  float b2 = b2p[t];
  float w3r[9];
#pragma unroll
  for (int j = 0; j < 9; ++j) w3r[j] = w3[j * 256 + t];
  float mem1 = 0.f, syn1 = 0.f, mem2 = 0.f, syn2 = 0.f;
  float syn3[9], mem3[9], pot[9];
#pragma unroll
  for (int j = 0; j < 9; ++j) { syn3[j] = 0.f; mem3[j] = 0.f; pot[j] = 0.f; }

#pragma unroll 1
  for (int step = 0; step < 10; ++step) {
    if (t < 128) {
      syn1 = ALPHA * syn1 + h1v;
      mem1 = BETA * mem1 + syn1;
      float s = (mem1 > 1.0f) ? 1.f : 0.f;
      spk1l[t] = s;
      mem1 -= s;
    }
    __syncthreads();
    // branchless: s in {0,1}; adding s*w (== +-0 when s==0) is bit-identical to
    // the conditional sum, but lets the compiler batch the 128 independent loads.
    float h2 = b2;
#pragma unroll
    for (int i = 0; i < 128; ++i) {
      h2 += spk1l[i] * w2T[i * 256 + t];
    }
    syn2 = ALPHA * syn2 + h2;
    mem2 = BETA * mem2 + syn2;
    float s2 = (mem2 > 1.0f) ? 1.f : 0.f;
    mem2 -= s2;

    float v[9];
#pragma unroll
    for (int j = 0; j < 9; ++j) v[j] = s2 * w3r[j];
#pragma unroll
    for (int j = 0; j < 9; ++j) {
      v[j] += __shfl_down(v[j], 32);
      v[j] += __shfl_down(v[j], 16);
      v[j] += __shfl_down(v[j], 8);
      v[j] += __shfl_down(v[j], 4);
      v[j] += __shfl_down(v[j], 2);
      v[j] += __shfl_down(v[j], 1);
    }
    if ((t & 63) == 0) {
#pragma unroll
      for (int j = 0; j < 9; ++j) part[t >> 6][j] = v[j];
    }
    __syncthreads();
    if (t == 0) {
#pragma unroll
      for (int j = 0; j < 9; ++j) {
        float h3 = part[0][j] + part[1][j] + part[2][j] + part[3][j] + b3p[j];
        syn3[j] = ALPHA * syn3[j] + h3;
        mem3[j] = BETA * mem3[j] + syn3[j];
        pot[j] += mem3[j];
      }
    }
  }
  if (t == 0) {
#pragma unroll
    for (int j = 0; j < 9; ++j) out[b * 9 + j] = pot[j] / 10.0f;
  }
}

// ---------------- host ----------------
extern "C" void kernel_launch(void* const* d_in, const int* in_sizes, int n_in,
                              void* d_out, int out_size, void* d_ws, size_t ws_size,
                              hipStream_t stream)
{
  const float* state = (const float*)d_in[0];
  const float* hist  = (const float*)d_in[1];
  const float* c1w   = (const float*)d_in[2];
  const float* c1b   = (const float*)d_in[3];
  const float* c2w   = (const float*)d_in[4];
  const float* c2b   = (const float*)d_in[5];
  const float* c3w   = (const float*)d_in[6];
  const float* c3b   = (const float*)d_in[7];
  const float* f1w   = (const float*)d_in[8];
  const float* f1b   = (const float*)d_in[9];
  const float* f2w   = (const float*)d_in[10];
  const float* f2b   = (const float*)d_in[11];
  const float* f3w   = (const float*)d_in[12];
  const float* f3b   = (const float*)d_in[13];
  float* out = (float*)d_out;
  float* ws  = (float*)d_ws;

  // workspace (float offsets), peak 27,045,888 floats (108.2 MB):
  //   sthi [0, 4,816,896) stlo [4,816,896, 9,633,792)       (quarter-batch state planes)
  //   c1hi [9,633,792, 12,731,392) c1lo [12,731,392, 15,828,992)  (quarter-batch)
  //   w1chi [15,828,992, 15,832,064) w1clo [15,832,064, 15,835,136)
  //   c2hi [15,835,136, 21,372,928) c2lo [21,372,928, 26,910,720) (full batch)
  //   w2hi [26,910,720, 26,927,104) w2lo [26,927,104, 26,943,488)
  //   w3hi [26,943,488, 26,961,920) w3lo [26,961,920, 26,980,352)
  //   h1 [26,980,352, 27,013,120) wT2 [27,013,120, 27,045,888)
  //   AFTER conv passes (state/c1/w1c dead):
  //   base_hi [0, 4,730,880) base_lo [4,730,880, 9,461,760)
  //   w1_hi [9,461,760, 11,827,200) w1_lo [11,827,200, 14,192,640)
  //   partb [14,192,640, 15,273,984)
  unsigned short* sthi    = (unsigned short*)(ws);
  unsigned short* stlo    = (unsigned short*)(ws + 4816896);
  unsigned short* c1hi    = (unsigned short*)(ws + 9633792);
  unsigned short* c1lo    = (unsigned short*)(ws + 12731392);
  unsigned short* w1chi   = (unsigned short*)(ws + 15828992);
  unsigned short* w1clo   = (unsigned short*)(ws + 15832064);
  unsigned short* c2hi    = (unsigned short*)(ws + 15835136);
  unsigned short* c2lo    = (unsigned short*)(ws + 21372928);
  unsigned short* w2_hi   = (unsigned short*)(ws + 26910720);
  unsigned short* w2_lo   = (unsigned short*)(ws + 26927104);
  unsigned short* w3_hi   = (unsigned short*)(ws + 26943488);
  unsigned short* w3_lo   = (unsigned short*)(ws + 26961920);
  float* h1buf    = ws + 26980352;
  float* wT2      = ws + 27013120;
  unsigned short* base_hi = (unsigned short*)(ws);
  unsigned short* base_lo = (unsigned short*)(ws + 4730880);
  unsigned short* w1_hi   = (unsigned short*)(ws + 9461760);
  unsigned short* w1_lo   = (unsigned short*)(ws + 11827200);
  float* partb    = ws + 14192640;

  convert_w1c<<<dim3(24), 256, 0, stream>>>(c1w, w1chi, w1clo);
  convert_w2<<<dim3(128), 256, 0, stream>>>(c2w, w2_hi, w2_lo);
  convert_w3<<<dim3(144), 256, 0, stream>>>(c3w, w3_hi, w3_lo);
  // quarter-batch conv1 -> conv2 passes
  for (int q = 0; q < 4; ++q) {
    convert_state<<<dim3(4704), 256, 0, stream>>>(state + (size_t)q * 9633792, sthi, stlo);
    conv1_mfma<<<dim3(16, 64), 256, 0, stream>>>(sthi, stlo, w1chi, w1clo, c1b, c1hi, c1lo);
    conv2_mfma<<<dim3(11, 64), 256, 0, stream>>>(c1hi, c1lo, w2_hi, w2_lo, c2b,
                                                 c2hi, c2lo, q * 64);
  }
  // state/c1/w1c dead -> region reused for base planes + w1 planes + partb
  convert_w1<<<dim3(9, 128), 256, 0, stream>>>(f1w, w1_hi, w1_lo);
  convert_w1_tail<<<dim3(128), 128, 0, stream>>>(f1w, w1_hi, w1_lo);
  fill_hist<<<dim3(256), 128, 0, stream>>>(hist, base_hi, base_lo);
  conv3_mfma<<<dim3(3, 256), 256, 0, stream>>>(c2hi, c2lo, w3_hi, w3_lo, c3b,
                                               base_hi, base_lo);
  transpose_fc2<<<dim3(128), 256, 0, stream>>>(f2w, wT2);
  fc1_mfma<<<dim3(16, 33), 256, 0, stream>>>(base_hi, base_lo, w1_hi, w1_lo, partb);
  fc1_reduce<<<dim3(128), 256, 0, stream>>>(partb, h1buf);
  snn_ker<<<dim3(256), 256, 0, stream>>>(h1buf, f1b, wT2, f2b, f3w, f3b, out);
}